// Round 1
// baseline (910.137 us; speedup 1.0000x reference)
//
#include <hip/hip_runtime.h>

typedef unsigned short u16;
typedef __attribute__((ext_vector_type(8))) short short8;
typedef __attribute__((ext_vector_type(4))) float floatx4;

#define S_TOT 2304
#define N_SEQ 2048
#define T_SEQ 256
#define C_DIM 1024
#define NH 16
#define DH 64
#define SIX_C 6144

__device__ __forceinline__ u16 f2bf(float f) {
  union { float f; unsigned u; } v; v.f = f;
  unsigned r = (v.u + 0x7FFFu + ((v.u >> 16) & 1u)) >> 16;
  return (u16)r;
}

__device__ __forceinline__ void async16(const void* g, void* l) {
  __builtin_amdgcn_global_load_lds((const __attribute__((address_space(1))) void*)g,
                                   (__attribute__((address_space(3))) void*)l, 16, 0, 0);
}

__device__ __forceinline__ floatx4 zero4() {
  floatx4 z; z[0] = 0.f; z[1] = 0.f; z[2] = 0.f; z[3] = 0.f; return z;
}

// XOR swizzles at 16B-chunk granularity (conflict-free-ish LDS layouts)
__device__ __forceinline__ int swzK(int r, int c) {      // 64-elem rows
  int ch = c >> 3; ch = (ch ^ r) & 7;
  return r * 64 + ch * 8 + (c & 7);
}
__device__ __forceinline__ int swzV(int r, int c) {      // 128-elem rows
  int ch = c >> 3; ch = (ch & 8) | ((ch ^ r) & 7);
  return r * 128 + ch * 8 + (c & 7);
}

// ---------------- adaLN modulation: m = silu(mod) @ w_adaln (k-split, atomic) --------------
__global__ __launch_bounds__(256)
void adaln_mod(const float* __restrict__ mod, const float* __restrict__ w,
               float* __restrict__ m) {
  __shared__ float sm[128];
  int b = blockIdx.y, kz = blockIdx.z;
  int tid = threadIdx.x;
  if (tid < 128) {
    float v = mod[b * C_DIM + kz * 128 + tid];
    sm[tid] = v / (1.f + __expf(-v));
  }
  __syncthreads();
  int j = blockIdx.x * 256 + tid;
  const float* wp = w + (size_t)(kz * 128) * SIX_C + j;
  float acc = 0.f;
  #pragma unroll 8
  for (int k = 0; k < 128; k++) acc += sm[k] * wp[(size_t)k * SIX_C];
  atomicAdd(&m[b * SIX_C + j], acc);
}

// ---------------- weight transpose + cast: W[K,N] fp32 -> Wt[N,K] bf16 ----------------
__global__ __launch_bounds__(256)
void wtrans(const float* __restrict__ W, u16* __restrict__ Wt, int K, int N) {
  __shared__ float t[32][33];
  int n0 = blockIdx.x << 5, k0 = blockIdx.y << 5;
  int tx = threadIdx.x & 31, ty = threadIdx.x >> 5;
  #pragma unroll
  for (int i = 0; i < 32; i += 8) {
    t[ty + i][tx] = W[(size_t)(k0 + ty + i) * N + n0 + tx];
  }
  __syncthreads();
  #pragma unroll
  for (int i = 0; i < 32; i += 8) {
    Wt[(size_t)(n0 + ty + i) * K + k0 + tx] = f2bf(t[tx][ty + i]);
  }
}

// ---------------- V[b,h,s,d] bf16 -> Vt[b,h,d,s] bf16 ----------------
__global__ __launch_bounds__(256)
void vtrans(const u16* __restrict__ V, u16* __restrict__ Vt) {
  __shared__ u16 t[64][65];
  int s0 = blockIdx.x << 6;
  int bh = blockIdx.y;
  const u16* src = V + (size_t)bh * S_TOT * DH;
  u16* dst = Vt + (size_t)bh * DH * S_TOT;
  int tid = threadIdx.x;
  #pragma unroll
  for (int i = 0; i < 16; i++) {
    int idx = tid + i * 256; int r = idx >> 6, c = idx & 63;
    t[r][c] = src[(size_t)(s0 + r) * DH + c];
  }
  __syncthreads();
  #pragma unroll
  for (int i = 0; i < 16; i++) {
    int idx = tid + i * 256; int r = idx >> 6, c = idx & 63;
    dst[(size_t)r * S_TOT + s0 + c] = t[c][r];
  }
}

// ---------------- LN1 + msa modulation -> joint bf16 ----------------
__global__ __launch_bounds__(256)
void ln_mod1(const float* __restrict__ x, const float* __restrict__ cond,
             const float* __restrict__ m, const float* __restrict__ ba,
             u16* __restrict__ joint) {
  int row = blockIdx.x;
  int b = row / S_TOT, s = row - b * S_TOT;
  const float* src = (s < N_SEQ) ? (x + (((size_t)(b * N_SEQ + s)) << 10))
                                 : (cond + (((size_t)(b * T_SEQ + (s - N_SEQ))) << 10));
  int tid = threadIdx.x;
  float4 v = ((const float4*)src)[tid];
  float s1 = v.x + v.y + v.z + v.w;
  float s2 = v.x * v.x + v.y * v.y + v.z * v.z + v.w * v.w;
  #pragma unroll
  for (int o = 32; o; o >>= 1) { s1 += __shfl_xor(s1, o); s2 += __shfl_xor(s2, o); }
  __shared__ float red[8];
  int wv = tid >> 6, ln = tid & 63;
  if (ln == 0) { red[wv] = s1; red[4 + wv] = s2; }
  __syncthreads();
  s1 = red[0] + red[1] + red[2] + red[3];
  s2 = red[4] + red[5] + red[6] + red[7];
  float mu = s1 * (1.f / 1024.f);
  float var = s2 * (1.f / 1024.f) - mu * mu;
  float rstd = rsqrtf(var + 1e-6f);
  int c = tid << 2;
  const float* mb = m + b * SIX_C;
  float4 sc = *(const float4*)(mb + 1024 + c);
  float4 sb = *(const float4*)(ba + 1024 + c);
  float4 sh = *(const float4*)(mb + c);
  float4 hb = *(const float4*)(ba + c);
  float y0 = (v.x - mu) * rstd * (1.f + sc.x + sb.x) + sh.x + hb.x;
  float y1 = (v.y - mu) * rstd * (1.f + sc.y + sb.y) + sh.y + hb.y;
  float y2 = (v.z - mu) * rstd * (1.f + sc.z + sb.z) + sh.z + hb.z;
  float y3 = (v.w - mu) * rstd * (1.f + sc.w + sb.w) + sh.w + hb.w;
  unsigned long long o = (unsigned long long)f2bf(y0)
      | ((unsigned long long)f2bf(y1) << 16)
      | ((unsigned long long)f2bf(y2) << 32)
      | ((unsigned long long)f2bf(y3) << 48);
  *(unsigned long long*)(joint + (((size_t)row) << 10) + c) = o;
}

// ---------------- LN2 + mlp modulation -> xln2/cln2 bf16 ----------------
__global__ __launch_bounds__(256)
void ln_mod2(const float* __restrict__ xin, const float* __restrict__ cin,
             const float* __restrict__ m, const float* __restrict__ ba,
             u16* __restrict__ xo, u16* __restrict__ co) {
  int row = blockIdx.x;
  int b = row / S_TOT, s = row - b * S_TOT;
  bool isx = (s < N_SEQ);
  size_t roff = isx ? (((size_t)(b * N_SEQ + s)) << 10)
                    : (((size_t)(b * T_SEQ + (s - N_SEQ))) << 10);
  const float* src = isx ? (xin + roff) : (cin + roff);
  int tid = threadIdx.x;
  float4 v = ((const float4*)src)[tid];
  float s1 = v.x + v.y + v.z + v.w;
  float s2 = v.x * v.x + v.y * v.y + v.z * v.z + v.w * v.w;
  #pragma unroll
  for (int o = 32; o; o >>= 1) { s1 += __shfl_xor(s1, o); s2 += __shfl_xor(s2, o); }
  __shared__ float red[8];
  int wv = tid >> 6, ln = tid & 63;
  if (ln == 0) { red[wv] = s1; red[4 + wv] = s2; }
  __syncthreads();
  s1 = red[0] + red[1] + red[2] + red[3];
  s2 = red[4] + red[5] + red[6] + red[7];
  float mu = s1 * (1.f / 1024.f);
  float var = s2 * (1.f / 1024.f) - mu * mu;
  float rstd = rsqrtf(var + 1e-6f);
  int c = tid << 2;
  const float* mb = m + b * SIX_C;
  float4 sc = *(const float4*)(mb + 4096 + c);
  float4 sb = *(const float4*)(ba + 4096 + c);
  float4 sh = *(const float4*)(mb + 3072 + c);
  float4 hb = *(const float4*)(ba + 3072 + c);
  float y0 = (v.x - mu) * rstd * (1.f + sc.x + sb.x) + sh.x + hb.x;
  float y1 = (v.y - mu) * rstd * (1.f + sc.y + sb.y) + sh.y + hb.y;
  float y2 = (v.z - mu) * rstd * (1.f + sc.z + sb.z) + sh.z + hb.z;
  float y3 = (v.w - mu) * rstd * (1.f + sc.w + sb.w) + sh.w + hb.w;
  unsigned long long o = (unsigned long long)f2bf(y0)
      | ((unsigned long long)f2bf(y1) << 16)
      | ((unsigned long long)f2bf(y2) << 32)
      | ((unsigned long long)f2bf(y3) << 48);
  u16* dst = isx ? (xo + roff) : (co + roff);
  *(unsigned long long*)(dst + c) = o;
}

// ---------------- GEMM: C = A[M,K] @ Bt[N,K]^T, bf16 in, fp32 acc, mode epilogues -------
// MODE 0: qkv scatter  1: proj+residual+gate  2: gelu->bf16  3: silu->bf16  4: d_out += val*g
template<int MODE>
__global__ __launch_bounds__(256)
void gemm_k(const u16* __restrict__ A, const u16* __restrict__ Bt,
            const float* __restrict__ bias, int M, int N, int K,
            const float* __restrict__ mvec, const float* __restrict__ ba,
            const float* __restrict__ rx, const float* __restrict__ rc,
            float* __restrict__ ox, float* __restrict__ oc,
            u16* __restrict__ oq, u16* __restrict__ okd, u16* __restrict__ ov,
            u16* __restrict__ obf, int rshift, int gofs)
{
  __shared__ alignas(16) u16 lA[128 * 32];
  __shared__ alignas(16) u16 lB[128 * 32];
  int tid = threadIdx.x;
  int wave = tid >> 6, lane = tid & 63, quad = lane >> 4, l15 = lane & 15;
  int bx = blockIdx.x, by = blockIdx.y;
  int wm = (wave >> 1) << 6, wn = (wave & 1) << 6;
  const u16* Ag = A + (size_t)(by << 7) * K;
  const u16* Bg = Bt + (size_t)(bx << 7) * K;
  floatx4 acc[4][4];
  #pragma unroll
  for (int i = 0; i < 4; i++) {
    #pragma unroll
    for (int j = 0; j < 4; j++) acc[i][j] = zero4();
  }

  for (int k0 = 0; k0 < K; k0 += 32) {
    #pragma unroll
    for (int i = 0; i < 2; i++) {
      int c = tid + (i << 8);
      async16(&Ag[(size_t)(c >> 2) * K + k0 + ((c & 3) << 3)], &lA[(size_t)c << 3]);
      async16(&Bg[(size_t)(c >> 2) * K + k0 + ((c & 3) << 3)], &lB[(size_t)c << 3]);
    }
    __syncthreads();
    short8 af[4], bfr[4];
    #pragma unroll
    for (int i = 0; i < 4; i++) {
      af[i]  = *(const short8*)&lA[(wm + (i << 4) + l15) * 32 + (quad << 3)];
      bfr[i] = *(const short8*)&lB[(wn + (i << 4) + l15) * 32 + (quad << 3)];
    }
    #pragma unroll
    for (int mi = 0; mi < 4; mi++) {
      #pragma unroll
      for (int ni = 0; ni < 4; ni++)
        acc[mi][ni] = __builtin_amdgcn_mfma_f32_16x16x32_bf16(af[mi], bfr[ni], acc[mi][ni], 0, 0, 0);
    }
    __syncthreads();
  }

  #pragma unroll
  for (int mi = 0; mi < 4; mi++) {
    #pragma unroll
    for (int r = 0; r < 4; r++) {
      int rg = (by << 7) + wm + (mi << 4) + (quad << 2) + r;
      if (MODE == 0) {
        int b = rg / S_TOT; int s = rg - b * S_TOT;
        #pragma unroll
        for (int ni = 0; ni < 4; ni++) {
          int col = (bx << 7) + wn + (ni << 4) + l15;
          float val = acc[mi][ni][r] + bias[col];
          int part = col >> 10, h = (col >> 6) & 15, d = col & 63;
          u16* dst = (part == 0) ? oq : (part == 1 ? okd : ov);
          dst[(((size_t)(b * NH + h)) * S_TOT + s) * DH + d] = f2bf(val);
        }
      } else if (MODE == 1) {
        int b = rg / S_TOT; int s = rg - b * S_TOT;
        #pragma unroll
        for (int ni = 0; ni < 4; ni++) {
          int col = (bx << 7) + wn + (ni << 4) + l15;
          float val = acc[mi][ni][r] + bias[col];
          float g = mvec[b * SIX_C + 2048 + col] + ba[2048 + col];
          if (s < N_SEQ) {
            size_t idx = (((size_t)(b * N_SEQ + s)) << 10) + col;
            ox[idx] = rx[idx] + val * g;
          } else {
            size_t idx = (((size_t)(b * T_SEQ + (s - N_SEQ))) << 10) + col;
            oc[idx] = rc[idx] + val * g;
          }
        }
      } else if (MODE == 2) {
        #pragma unroll
        for (int ni = 0; ni < 4; ni++) {
          int col = (bx << 7) + wn + (ni << 4) + l15;
          float t = acc[mi][ni][r] + bias[col];
          float u = 0.7978845608028654f * (t + 0.044715f * t * t * t);
          float e = __expf(2.f * u);
          float th = 1.f - 2.f / (e + 1.f);
          obf[(size_t)rg * N + col] = f2bf(0.5f * t * (1.f + th));
        }
      } else if (MODE == 3) {
        #pragma unroll
        for (int ni = 0; ni < 4; ni++) {
          int col = (bx << 7) + wn + (ni << 4) + l15;
          float t = acc[mi][ni][r] + bias[col];
          obf[(size_t)rg * N + col] = f2bf(t / (1.f + __expf(-t)));
        }
      } else {  // MODE 4
        int b = rg >> rshift;
        #pragma unroll
        for (int ni = 0; ni < 4; ni++) {
          int col = (bx << 7) + wn + (ni << 4) + l15;
          float val = acc[mi][ni][r] + bias[col];
          float g = mvec[b * SIX_C + gofs + col] + ba[gofs + col];
          size_t idx = (((size_t)rg) << 10) + col;
          ox[idx] += val * g;
        }
      }
    }
  }
}

// ---------------- flash attention ----------------
__global__ __launch_bounds__(256)
void flash_attn(const u16* __restrict__ Q, const u16* __restrict__ K,
                const u16* __restrict__ V, u16* __restrict__ O) {
  __shared__ alignas(16) u16 lK[128 * 64];
  __shared__ alignas(16) u16 lV[64 * 128];
  __shared__ alignas(16) u16 lP[4 * 32 * 128];
  int tid = threadIdx.x;
  int wave = tid >> 6, lane = tid & 63, quad = lane >> 4, l15 = lane & 15;
  int q0 = blockIdx.x << 7;
  int bh = blockIdx.y;
  const u16* Qb = Q + (size_t)bh * S_TOT * DH;
  const u16* Kb = K + (size_t)bh * S_TOT * DH;
  const u16* Vb = V + (size_t)bh * DH * S_TOT;

  short8 qf[2][2];
  #pragma unroll
  for (int mi = 0; mi < 2; mi++) {
    #pragma unroll
    for (int ks = 0; ks < 2; ks++)
      qf[mi][ks] = *(const short8*)&Qb[(size_t)(q0 + wave * 32 + mi * 16 + l15) * DH + ks * 32 + quad * 8];
  }

  floatx4 oacc[2][4];
  #pragma unroll
  for (int mi = 0; mi < 2; mi++) {
    #pragma unroll
    for (int nd = 0; nd < 4; nd++) oacc[mi][nd] = zero4();
  }
  float mst[8], lst[8];
  #pragma unroll
  for (int i = 0; i < 8; i++) { mst[i] = -1e30f; lst[i] = 0.f; }

  u16* lPw = lP + wave * 4096;

  for (int kv0 = 0; kv0 < S_TOT; kv0 += 128) {
    #pragma unroll
    for (int i = 0; i < 4; i++) {
      int c = tid + i * 256;
      int r = c >> 3, col = (c & 7) << 3;
      *(short8*)&lK[swzK(r, col)] = *(const short8*)&Kb[(size_t)(kv0 + r) * DH + col];
      int r2 = c >> 4, col2 = (c & 15) << 3;
      *(short8*)&lV[swzV(r2, col2)] = *(const short8*)&Vb[(size_t)r2 * S_TOT + kv0 + col2];
    }
    __syncthreads();

    floatx4 sacc[2][8];
    #pragma unroll
    for (int mi = 0; mi < 2; mi++) {
      #pragma unroll
      for (int ni = 0; ni < 8; ni++) sacc[mi][ni] = zero4();
    }
    #pragma unroll
    for (int ks = 0; ks < 2; ks++) {
      #pragma unroll
      for (int ni = 0; ni < 8; ni++) {
        short8 bf = *(const short8*)&lK[swzK(ni * 16 + l15, ks * 32 + quad * 8)];
        sacc[0][ni] = __builtin_amdgcn_mfma_f32_16x16x32_bf16(qf[0][ks], bf, sacc[0][ni], 0, 0, 0);
        sacc[1][ni] = __builtin_amdgcn_mfma_f32_16x16x32_bf16(qf[1][ks], bf, sacc[1][ni], 0, 0, 0);
      }
    }
    #pragma unroll
    for (int mi = 0; mi < 2; mi++) {
      #pragma unroll
      for (int r = 0; r < 4; r++) {
        int si = mi * 4 + r;
        float rm = -1e30f;
        #pragma unroll
        for (int ni = 0; ni < 8; ni++) {
          float v = sacc[mi][ni][r] * 0.125f;
          sacc[mi][ni][r] = v;
          rm = fmaxf(rm, v);
        }
        rm = fmaxf(rm, __shfl_xor(rm, 1));
        rm = fmaxf(rm, __shfl_xor(rm, 2));
        rm = fmaxf(rm, __shfl_xor(rm, 4));
        rm = fmaxf(rm, __shfl_xor(rm, 8));
        float mnew = fmaxf(mst[si], rm);
        float al = __expf(mst[si] - mnew);
        mst[si] = mnew;
        float rs = 0.f;
        #pragma unroll
        for (int ni = 0; ni < 8; ni++) {
          float p = __expf(sacc[mi][ni][r] - mnew);
          sacc[mi][ni][r] = p;
          rs += p;
        }
        rs += __shfl_xor(rs, 1);
        rs += __shfl_xor(rs, 2);
        rs += __shfl_xor(rs, 4);
        rs += __shfl_xor(rs, 8);
        lst[si] = lst[si] * al + rs;
        #pragma unroll
        for (int nd = 0; nd < 4; nd++) oacc[mi][nd][r] *= al;
        int rowl = mi * 16 + quad * 4 + r;
        #pragma unroll
        for (int ni = 0; ni < 8; ni++)
          lPw[swzV(rowl, ni * 16 + l15)] = f2bf(sacc[mi][ni][r]);
      }
    }
    #pragma unroll
    for (int kk = 0; kk < 4; kk++) {
      short8 pf0 = *(const short8*)&lPw[swzV(l15, kk * 32 + quad * 8)];
      short8 pf1 = *(const short8*)&lPw[swzV(16 + l15, kk * 32 + quad * 8)];
      #pragma unroll
      for (int nd = 0; nd < 4; nd++) {
        short8 vf = *(const short8*)&lV[swzV(nd * 16 + l15, kk * 32 + quad * 8)];
        oacc[0][nd] = __builtin_amdgcn_mfma_f32_16x16x32_bf16(pf0, vf, oacc[0][nd], 0, 0, 0);
        oacc[1][nd] = __builtin_amdgcn_mfma_f32_16x16x32_bf16(pf1, vf, oacc[1][nd], 0, 0, 0);
      }
    }
    __syncthreads();
  }

  int b = bh >> 4, h = bh & 15;
  #pragma unroll
  for (int mi = 0; mi < 2; mi++) {
    #pragma unroll
    for (int r = 0; r < 4; r++) {
      float inv = 1.f / lst[mi * 4 + r];
      int srow = q0 + wave * 32 + mi * 16 + quad * 4 + r;
      size_t base = (((size_t)(b * S_TOT + srow)) << 10) + h * 64;
      #pragma unroll
      for (int nd = 0; nd < 4; nd++)
        O[base + nd * 16 + l15] = f2bf(oacc[mi][nd][r] * inv);
    }
  }
}

// ---------------- launch ----------------
extern "C" void kernel_launch(void* const* d_in, const int* in_sizes, int n_in,
                              void* d_out, int out_size, void* d_ws, size_t ws_size,
                              hipStream_t stream) {
  const float* x       = (const float*)d_in[0];
  const float* mod     = (const float*)d_in[1];
  const float* cond    = (const float*)d_in[2];
  const float* w_adaln = (const float*)d_in[3];
  const float* b_adaln = (const float*)d_in[4];
  const float* w_qkv   = (const float*)d_in[5];
  const float* b_qkv   = (const float*)d_in[6];
  const float* w_proj  = (const float*)d_in[7];
  const float* b_proj  = (const float*)d_in[8];
  const float* w_s1    = (const float*)d_in[9];
  const float* b_s1    = (const float*)d_in[10];
  const float* w_s2    = (const float*)d_in[11];
  const float* b_s2    = (const float*)d_in[12];
  const float* w_d1    = (const float*)d_in[13];
  const float* b_d1    = (const float*)d_in[14];
  const float* w_d2    = (const float*)d_in[15];
  const float* b_d2    = (const float*)d_in[16];

  float* outx = (float*)d_out;
  float* outc = outx + (size_t)2 * N_SEQ * C_DIM;

  char* w = (char*)d_ws;
  auto alloc = [&](size_t bytes) { char* p = w; w += (bytes + 255) & ~(size_t)255; return p; };
  float* m_ws  = (float*)alloc(12288 * 4);
  u16* wqkvT   = (u16*)alloc((size_t)3072 * 1024 * 2);
  u16* wprojT  = (u16*)alloc((size_t)1024 * 1024 * 2);
  u16* ws1T    = (u16*)alloc((size_t)4096 * 1024 * 2);
  u16* ws2T    = (u16*)alloc((size_t)4096 * 1024 * 2);
  u16* wd1T    = (u16*)alloc((size_t)4096 * 1024 * 2);
  u16* wd2T    = (u16*)alloc((size_t)4096 * 1024 * 2);
  u16* joint   = (u16*)alloc((size_t)4608 * 1024 * 2);   // also reused as attn_out
  u16* Qb      = (u16*)alloc((size_t)4718592 * 2);
  u16* Kb      = (u16*)alloc((size_t)4718592 * 2);
  u16* Vb      = (u16*)alloc((size_t)4718592 * 2);
  u16* Vtb     = (u16*)alloc((size_t)4718592 * 2);
  u16* h1x     = (u16*)alloc((size_t)4096 * 4096 * 2);
  u16* h1c     = (u16*)alloc((size_t)512 * 4096 * 2);
  u16* xln2 = Qb;       // alias: Q dead after flash
  u16* cln2 = Kb;       // alias: K dead after flash
  u16* attn_out = joint;

  size_t needed = (size_t)(w - (char*)d_ws);
  if (needed > ws_size) {  // distinctive failure mode: zero output
    hipMemsetAsync(d_out, 0, (size_t)out_size * 4, stream);
    return;
  }

  hipMemsetAsync(m_ws, 0, 12288 * 4, stream);
  adaln_mod<<<dim3(24, 2, 8), 256, 0, stream>>>(mod, w_adaln, m_ws);

  wtrans<<<dim3(96, 32), 256, 0, stream>>>(w_qkv, wqkvT, 1024, 3072);
  wtrans<<<dim3(32, 32), 256, 0, stream>>>(w_proj, wprojT, 1024, 1024);
  wtrans<<<dim3(128, 32), 256, 0, stream>>>(w_s1, ws1T, 1024, 4096);
  wtrans<<<dim3(32, 128), 256, 0, stream>>>(w_s2, ws2T, 4096, 1024);
  wtrans<<<dim3(128, 32), 256, 0, stream>>>(w_d1, wd1T, 1024, 4096);
  wtrans<<<dim3(32, 128), 256, 0, stream>>>(w_d2, wd2T, 4096, 1024);

  ln_mod1<<<4608, 256, 0, stream>>>(x, cond, m_ws, b_adaln, joint);

  gemm_k<0><<<dim3(24, 36), 256, 0, stream>>>(joint, wqkvT, b_qkv, 4608, 3072, 1024,
      nullptr, nullptr, nullptr, nullptr, nullptr, nullptr, Qb, Kb, Vb, nullptr, 0, 0);

  vtrans<<<dim3(36, 32), 256, 0, stream>>>(Vb, Vtb);
  flash_attn<<<dim3(18, 32), 256, 0, stream>>>(Qb, Kb, Vtb, attn_out);

  gemm_k<1><<<dim3(8, 36), 256, 0, stream>>>(attn_out, wprojT, b_proj, 4608, 1024, 1024,
      m_ws, b_adaln, x, cond, outx, outc, nullptr, nullptr, nullptr, nullptr, 0, 0);

  ln_mod2<<<4608, 256, 0, stream>>>(outx, outc, m_ws, b_adaln, xln2, cln2);

  gemm_k<2><<<dim3(32, 32), 256, 0, stream>>>(xln2, ws1T, b_s1, 4096, 4096, 1024,
      nullptr, nullptr, nullptr, nullptr, nullptr, nullptr, nullptr, nullptr, nullptr, h1x, 0, 0);
  gemm_k<4><<<dim3(8, 32), 256, 0, stream>>>(h1x, ws2T, b_s2, 4096, 1024, 4096,
      m_ws, b_adaln, nullptr, nullptr, outx, nullptr, nullptr, nullptr, nullptr, nullptr, 11, 5120);

  gemm_k<3><<<dim3(32, 4), 256, 0, stream>>>(cln2, wd1T, b_d1, 512, 4096, 1024,
      nullptr, nullptr, nullptr, nullptr, nullptr, nullptr, nullptr, nullptr, nullptr, h1c, 0, 0);
  gemm_k<4><<<dim3(8, 4), 256, 0, stream>>>(h1c, wd2T, b_d2, 512, 1024, 4096,
      m_ws, b_adaln, nullptr, nullptr, outc, nullptr, nullptr, nullptr, nullptr, nullptr, 8, 5120);
}

// Round 2
// 691.401 us; speedup vs baseline: 1.3164x; 1.3164x over previous
//
#include <hip/hip_runtime.h>

typedef unsigned short u16;
typedef __attribute__((ext_vector_type(8))) short short8;
typedef __attribute__((ext_vector_type(4))) short s4b;
typedef __attribute__((ext_vector_type(4))) float floatx4;

#define S_TOT 2304
#define N_SEQ 2048
#define T_SEQ 256
#define C_DIM 1024
#define NH 16
#define DH 64
#define SIX_C 6144

__device__ __forceinline__ u16 f2bf(float f) {
  union { float f; unsigned u; } v; v.f = f;
  unsigned r = (v.u + 0x7FFFu + ((v.u >> 16) & 1u)) >> 16;
  return (u16)r;
}
__device__ __forceinline__ float bf2f(u16 u) {
  union { unsigned u; float f; } v; v.u = ((unsigned)u) << 16; return v.f;
}

__device__ __forceinline__ void async16(const void* g, void* l) {
  __builtin_amdgcn_global_load_lds((const __attribute__((address_space(1))) void*)g,
                                   (__attribute__((address_space(3))) void*)l, 16, 0, 0);
}

__device__ __forceinline__ floatx4 zero4() {
  floatx4 z; z[0] = 0.f; z[1] = 0.f; z[2] = 0.f; z[3] = 0.f; return z;
}

// ---------------- adaLN modulation: m = silu(mod) @ w_adaln (k-split, atomic) --------------
__global__ __launch_bounds__(256)
void adaln_mod(const float* __restrict__ mod, const float* __restrict__ w,
               float* __restrict__ m) {
  __shared__ float sm[128];
  int b = blockIdx.y, kz = blockIdx.z;
  int tid = threadIdx.x;
  if (tid < 128) {
    float v = mod[b * C_DIM + kz * 128 + tid];
    sm[tid] = v / (1.f + __expf(-v));
  }
  __syncthreads();
  int j = blockIdx.x * 256 + tid;
  const float* wp = w + (size_t)(kz * 128) * SIX_C + j;
  float acc = 0.f;
  #pragma unroll 8
  for (int k = 0; k < 128; k++) acc += sm[k] * wp[(size_t)k * SIX_C];
  atomicAdd(&m[b * SIX_C + j], acc);
}

// ---------------- weight transpose + cast: W[K,N] fp32 -> Wt[N,K] bf16 ----------------
__global__ __launch_bounds__(256)
void wtrans(const float* __restrict__ W, u16* __restrict__ Wt, int K, int N) {
  __shared__ float t[32][33];
  int n0 = blockIdx.x << 5, k0 = blockIdx.y << 5;
  int tx = threadIdx.x & 31, ty = threadIdx.x >> 5;
  #pragma unroll
  for (int i = 0; i < 32; i += 8) {
    t[ty + i][tx] = W[(size_t)(k0 + ty + i) * N + n0 + tx];
  }
  __syncthreads();
  #pragma unroll
  for (int i = 0; i < 32; i += 8) {
    Wt[(size_t)(n0 + ty + i) * K + k0 + tx] = f2bf(t[tx][ty + i]);
  }
}

// ---------------- V[b,h,s,d] bf16 -> Vt[b,h,d,s] bf16 ----------------
__global__ __launch_bounds__(256)
void vtrans(const u16* __restrict__ V, u16* __restrict__ Vt) {
  __shared__ u16 t[64][65];
  int s0 = blockIdx.x << 6;
  int bh = blockIdx.y;
  const u16* src = V + (size_t)bh * S_TOT * DH;
  u16* dst = Vt + (size_t)bh * DH * S_TOT;
  int tid = threadIdx.x;
  #pragma unroll
  for (int i = 0; i < 16; i++) {
    int idx = tid + i * 256; int r = idx >> 6, c = idx & 63;
    t[r][c] = src[(size_t)(s0 + r) * DH + c];
  }
  __syncthreads();
  #pragma unroll
  for (int i = 0; i < 16; i++) {
    int idx = tid + i * 256; int r = idx >> 6, c = idx & 63;
    dst[(size_t)r * S_TOT + s0 + c] = t[c][r];
  }
}

// ---------------- LN1 + msa modulation -> joint bf16 ----------------
__global__ __launch_bounds__(256)
void ln_mod1(const float* __restrict__ x, const float* __restrict__ cond,
             const float* __restrict__ m, const float* __restrict__ ba,
             u16* __restrict__ joint) {
  int row = blockIdx.x;
  int b = row / S_TOT, s = row - b * S_TOT;
  const float* src = (s < N_SEQ) ? (x + (((size_t)(b * N_SEQ + s)) << 10))
                                 : (cond + (((size_t)(b * T_SEQ + (s - N_SEQ))) << 10));
  int tid = threadIdx.x;
  float4 v = ((const float4*)src)[tid];
  float s1 = v.x + v.y + v.z + v.w;
  float s2 = v.x * v.x + v.y * v.y + v.z * v.z + v.w * v.w;
  #pragma unroll
  for (int o = 32; o; o >>= 1) { s1 += __shfl_xor(s1, o); s2 += __shfl_xor(s2, o); }
  __shared__ float red[8];
  int wv = tid >> 6, ln = tid & 63;
  if (ln == 0) { red[wv] = s1; red[4 + wv] = s2; }
  __syncthreads();
  s1 = red[0] + red[1] + red[2] + red[3];
  s2 = red[4] + red[5] + red[6] + red[7];
  float mu = s1 * (1.f / 1024.f);
  float var = s2 * (1.f / 1024.f) - mu * mu;
  float rstd = rsqrtf(var + 1e-6f);
  int c = tid << 2;
  const float* mb = m + b * SIX_C;
  float4 sc = *(const float4*)(mb + 1024 + c);
  float4 sb = *(const float4*)(ba + 1024 + c);
  float4 sh = *(const float4*)(mb + c);
  float4 hb = *(const float4*)(ba + c);
  float y0 = (v.x - mu) * rstd * (1.f + sc.x + sb.x) + sh.x + hb.x;
  float y1 = (v.y - mu) * rstd * (1.f + sc.y + sb.y) + sh.y + hb.y;
  float y2 = (v.z - mu) * rstd * (1.f + sc.z + sb.z) + sh.z + hb.z;
  float y3 = (v.w - mu) * rstd * (1.f + sc.w + sb.w) + sh.w + hb.w;
  unsigned long long o = (unsigned long long)f2bf(y0)
      | ((unsigned long long)f2bf(y1) << 16)
      | ((unsigned long long)f2bf(y2) << 32)
      | ((unsigned long long)f2bf(y3) << 48);
  *(unsigned long long*)(joint + (((size_t)row) << 10) + c) = o;
}

// ---------------- LN2 + mlp modulation -> xln2/cln2 bf16 ----------------
__global__ __launch_bounds__(256)
void ln_mod2(const float* __restrict__ xin, const float* __restrict__ cin,
             const float* __restrict__ m, const float* __restrict__ ba,
             u16* __restrict__ xo, u16* __restrict__ co) {
  int row = blockIdx.x;
  int b = row / S_TOT, s = row - b * S_TOT;
  bool isx = (s < N_SEQ);
  size_t roff = isx ? (((size_t)(b * N_SEQ + s)) << 10)
                    : (((size_t)(b * T_SEQ + (s - N_SEQ))) << 10);
  const float* src = isx ? (xin + roff) : (cin + roff);
  int tid = threadIdx.x;
  float4 v = ((const float4*)src)[tid];
  float s1 = v.x + v.y + v.z + v.w;
  float s2 = v.x * v.x + v.y * v.y + v.z * v.z + v.w * v.w;
  #pragma unroll
  for (int o = 32; o; o >>= 1) { s1 += __shfl_xor(s1, o); s2 += __shfl_xor(s2, o); }
  __shared__ float red[8];
  int wv = tid >> 6, ln = tid & 63;
  if (ln == 0) { red[wv] = s1; red[4 + wv] = s2; }
  __syncthreads();
  s1 = red[0] + red[1] + red[2] + red[3];
  s2 = red[4] + red[5] + red[6] + red[7];
  float mu = s1 * (1.f / 1024.f);
  float var = s2 * (1.f / 1024.f) - mu * mu;
  float rstd = rsqrtf(var + 1e-6f);
  int c = tid << 2;
  const float* mb = m + b * SIX_C;
  float4 sc = *(const float4*)(mb + 4096 + c);
  float4 sb = *(const float4*)(ba + 4096 + c);
  float4 sh = *(const float4*)(mb + 3072 + c);
  float4 hb = *(const float4*)(ba + 3072 + c);
  float y0 = (v.x - mu) * rstd * (1.f + sc.x + sb.x) + sh.x + hb.x;
  float y1 = (v.y - mu) * rstd * (1.f + sc.y + sb.y) + sh.y + hb.y;
  float y2 = (v.z - mu) * rstd * (1.f + sc.z + sb.z) + sh.z + hb.z;
  float y3 = (v.w - mu) * rstd * (1.f + sc.w + sb.w) + sh.w + hb.w;
  unsigned long long o = (unsigned long long)f2bf(y0)
      | ((unsigned long long)f2bf(y1) << 16)
      | ((unsigned long long)f2bf(y2) << 32)
      | ((unsigned long long)f2bf(y3) << 48);
  u16* dst = isx ? (xo + roff) : (co + roff);
  *(unsigned long long*)(dst + c) = o;
}

// ---------------- GEMM: C = A[M,K] @ Bt[N,K]^T, bf16 in, fp32 acc, mode epilogues -------
// MODE 0: qkv scatter  1: proj+residual+gate  2: gelu->bf16  3: silu->bf16  4: d_out += val*g
template<int MODE>
__global__ __launch_bounds__(256)
void gemm_k(const u16* __restrict__ A, const u16* __restrict__ Bt,
            const float* __restrict__ bias, int M, int N, int K,
            const float* __restrict__ mvec, const float* __restrict__ ba,
            const float* __restrict__ rx, const float* __restrict__ rc,
            float* __restrict__ ox, float* __restrict__ oc,
            u16* __restrict__ oq, u16* __restrict__ okd, u16* __restrict__ ov,
            u16* __restrict__ obf, int rshift, int gofs)
{
  __shared__ alignas(16) u16 lA[128 * 32];
  __shared__ alignas(16) u16 lB[128 * 32];
  int tid = threadIdx.x;
  int wave = tid >> 6, lane = tid & 63, quad = lane >> 4, l15 = lane & 15;
  int bx = blockIdx.x, by = blockIdx.y;
  int wm = (wave >> 1) << 6, wn = (wave & 1) << 6;
  const u16* Ag = A + (size_t)(by << 7) * K;
  const u16* Bg = Bt + (size_t)(bx << 7) * K;
  floatx4 acc[4][4];
  #pragma unroll
  for (int i = 0; i < 4; i++) {
    #pragma unroll
    for (int j = 0; j < 4; j++) acc[i][j] = zero4();
  }

  for (int k0 = 0; k0 < K; k0 += 32) {
    #pragma unroll
    for (int i = 0; i < 2; i++) {
      int c = tid + (i << 8);
      async16(&Ag[(size_t)(c >> 2) * K + k0 + ((c & 3) << 3)], &lA[(size_t)c << 3]);
      async16(&Bg[(size_t)(c >> 2) * K + k0 + ((c & 3) << 3)], &lB[(size_t)c << 3]);
    }
    __syncthreads();
    short8 af[4], bfr[4];
    #pragma unroll
    for (int i = 0; i < 4; i++) {
      af[i]  = *(const short8*)&lA[(wm + (i << 4) + l15) * 32 + (quad << 3)];
      bfr[i] = *(const short8*)&lB[(wn + (i << 4) + l15) * 32 + (quad << 3)];
    }
    #pragma unroll
    for (int mi = 0; mi < 4; mi++) {
      #pragma unroll
      for (int ni = 0; ni < 4; ni++)
        acc[mi][ni] = __builtin_amdgcn_mfma_f32_16x16x32_bf16(af[mi], bfr[ni], acc[mi][ni], 0, 0, 0);
    }
    __syncthreads();
  }

  #pragma unroll
  for (int mi = 0; mi < 4; mi++) {
    #pragma unroll
    for (int r = 0; r < 4; r++) {
      int rg = (by << 7) + wm + (mi << 4) + (quad << 2) + r;
      if (MODE == 0) {
        int b = rg / S_TOT; int s = rg - b * S_TOT;
        #pragma unroll
        for (int ni = 0; ni < 4; ni++) {
          int col = (bx << 7) + wn + (ni << 4) + l15;
          float val = acc[mi][ni][r] + bias[col];
          int part = col >> 10, h = (col >> 6) & 15, d = col & 63;
          u16* dst = (part == 0) ? oq : (part == 1 ? okd : ov);
          dst[(((size_t)(b * NH + h)) * S_TOT + s) * DH + d] = f2bf(val);
        }
      } else if (MODE == 1) {
        int b = rg / S_TOT; int s = rg - b * S_TOT;
        #pragma unroll
        for (int ni = 0; ni < 4; ni++) {
          int col = (bx << 7) + wn + (ni << 4) + l15;
          float val = acc[mi][ni][r] + bias[col];
          float g = mvec[b * SIX_C + 2048 + col] + ba[2048 + col];
          if (s < N_SEQ) {
            size_t idx = (((size_t)(b * N_SEQ + s)) << 10) + col;
            ox[idx] = rx[idx] + val * g;
          } else {
            size_t idx = (((size_t)(b * T_SEQ + (s - N_SEQ))) << 10) + col;
            oc[idx] = rc[idx] + val * g;
          }
        }
      } else if (MODE == 2) {
        #pragma unroll
        for (int ni = 0; ni < 4; ni++) {
          int col = (bx << 7) + wn + (ni << 4) + l15;
          float t = acc[mi][ni][r] + bias[col];
          float u = 0.7978845608028654f * (t + 0.044715f * t * t * t);
          float e = __expf(2.f * u);
          float th = 1.f - 2.f / (e + 1.f);
          obf[(size_t)rg * N + col] = f2bf(0.5f * t * (1.f + th));
        }
      } else if (MODE == 3) {
        #pragma unroll
        for (int ni = 0; ni < 4; ni++) {
          int col = (bx << 7) + wn + (ni << 4) + l15;
          float t = acc[mi][ni][r] + bias[col];
          obf[(size_t)rg * N + col] = f2bf(t / (1.f + __expf(-t)));
        }
      } else {  // MODE 4
        int b = rg >> rshift;
        #pragma unroll
        for (int ni = 0; ni < 4; ni++) {
          int col = (bx << 7) + wn + (ni << 4) + l15;
          float val = acc[mi][ni][r] + bias[col];
          float g = mvec[b * SIX_C + gofs + col] + ba[gofs + col];
          size_t idx = (((size_t)rg) << 10) + col;
          ox[idx] += val * g;
        }
      }
    }
  }
}

// ---------------- flash attention (S^T trick: P exits QK^T in PV B-operand layout) -------
// Per block: 128 q rows, full kv sweep. Wave w owns q rows [w*32, w*32+32).
// S^T = K·Q^T via mfma_16x16x32 (A=K frag, B=Q frag): C col=lane&15=q, row=quad*4+r=s.
// That IS the B-operand layout of mfma_f32_16x16x16bf16_1k (n=lane&15, k=quad*4+j).
// O^T = V^T·P^T via _1k (A=V^T frag from LDS). No LDS round-trip for P.
__global__ __launch_bounds__(256)
void flash_attn(const u16* __restrict__ Q, const u16* __restrict__ K,
                const u16* __restrict__ V, u16* __restrict__ O) {
  __shared__ alignas(16) u16 lK[128 * 64];   // [s][d], chunk-xor-swizzled
  __shared__ alignas(16) u16 lV[64 * 128];   // [d][s], chunk-xor-swizzled
  int tid = threadIdx.x;
  int wave = tid >> 6, lane = tid & 63, quad = lane >> 4, l15 = lane & 15;
  int q0 = blockIdx.x << 7;
  int bh = blockIdx.y;
  const u16* Qb = Q + (size_t)bh * S_TOT * DH;
  const u16* Kb = K + (size_t)bh * S_TOT * DH;
  const u16* Vb = V + (size_t)bh * DH * S_TOT;

  // Q fragments, pre-scaled by 1/sqrt(D)=0.125. B-layout for x32: n=l15=q, k=quad*8+j.
  short8 qf[2][2];
  #pragma unroll
  for (int mi = 0; mi < 2; mi++) {
    const u16* qrow = Qb + (size_t)(q0 + wave * 32 + mi * 16 + l15) * DH;
    #pragma unroll
    for (int kd = 0; kd < 2; kd++) {
      short8 raw = *(const short8*)&qrow[kd * 32 + quad * 8];
      short8 sc;
      #pragma unroll
      for (int j = 0; j < 8; j++) sc[j] = (short)f2bf(bf2f((u16)raw[j]) * 0.125f);
      qf[mi][kd] = sc;
    }
  }

  floatx4 oacc[2][4];   // O^T acc: [mi(q-tile)][dt(d-tile)]; col=q, row=d
  #pragma unroll
  for (int mi = 0; mi < 2; mi++)
    #pragma unroll
    for (int dt = 0; dt < 4; dt++) oacc[mi][dt] = zero4();
  float mst[2] = {-1e30f, -1e30f}, lst[2] = {0.f, 0.f};

  for (int kv0 = 0; kv0 < S_TOT; kv0 += 128) {
    // stage K tile [128 s][64 d] and V^T tile [64 d][128 s], source-chunk-xor swizzle
    #pragma unroll
    for (int i = 0; i < 4; i++) {
      int ci = tid + (i << 8);
      int rK = ci >> 3, clK = ci & 7;
      int cgK = clK ^ (rK & 7);
      async16(&Kb[(size_t)(kv0 + rK) * DH + (cgK << 3)], &lK[(size_t)ci << 3]);
      int rV = ci >> 4, clV = ci & 15;
      int cgV = (clV & 8) | ((clV ^ (rV & 7)) & 7);
      async16(&Vb[(size_t)rV * S_TOT + kv0 + (cgV << 3)], &lV[(size_t)ci << 3]);
    }
    __syncthreads();

    // S^T: sacc[mi][si], s = si*16 + quad*4 + r, q = l15 (per lane: 1 q, 64 s-vals)
    floatx4 sacc[2][8];
    #pragma unroll
    for (int mi = 0; mi < 2; mi++)
      #pragma unroll
      for (int si = 0; si < 8; si++) sacc[mi][si] = zero4();
    #pragma unroll
    for (int si = 0; si < 8; si++) {
      int r = si * 16 + l15;
      #pragma unroll
      for (int kd = 0; kd < 2; kd++) {
        int c = (kd << 2) + quad;
        int cl = c ^ (r & 7);
        short8 kf = *(const short8*)&lK[r * 64 + (cl << 3)];
        sacc[0][si] = __builtin_amdgcn_mfma_f32_16x16x32_bf16(kf, qf[0][kd], sacc[0][si], 0, 0, 0);
        sacc[1][si] = __builtin_amdgcn_mfma_f32_16x16x32_bf16(kf, qf[1][kd], sacc[1][si], 0, 0, 0);
      }
    }

    // online softmax, all lane-local except 2 shuffles per reduction
    #pragma unroll
    for (int mi = 0; mi < 2; mi++) {
      float rm = -1e30f;
      #pragma unroll
      for (int si = 0; si < 8; si++)
        #pragma unroll
        for (int r = 0; r < 4; r++) rm = fmaxf(rm, sacc[mi][si][r]);
      rm = fmaxf(rm, __shfl_xor(rm, 16));
      rm = fmaxf(rm, __shfl_xor(rm, 32));
      float mnew = fmaxf(mst[mi], rm);
      float al = __expf(mst[mi] - mnew);
      mst[mi] = mnew;
      float rs = 0.f;
      #pragma unroll
      for (int si = 0; si < 8; si++)
        #pragma unroll
        for (int r = 0; r < 4; r++) {
          float p = __expf(sacc[mi][si][r] - mnew);
          sacc[mi][si][r] = p;
          rs += p;
        }
      rs += __shfl_xor(rs, 16);
      rs += __shfl_xor(rs, 32);
      lst[mi] = lst[mi] * al + rs;
      #pragma unroll
      for (int dt = 0; dt < 4; dt++)
        #pragma unroll
        for (int r = 0; r < 4; r++) oacc[mi][dt][r] *= al;
    }

    // O^T += V^T · P^T  (A=V^T frag: m=d=l15+dt*16, k=s=quad*4+j; B=packed P)
    #pragma unroll
    for (int si = 0; si < 8; si++) {
      s4b pb[2];
      #pragma unroll
      for (int mi = 0; mi < 2; mi++) {
        s4b p;
        #pragma unroll
        for (int r = 0; r < 4; r++) p[r] = (short)f2bf(sacc[mi][si][r]);
        pb[mi] = p;
      }
      #pragma unroll
      for (int dt = 0; dt < 4; dt++) {
        int r = dt * 16 + l15;
        int c = (si << 1) + (quad >> 1);
        int cl = (c & 8) | ((c ^ (r & 7)) & 7);
        s4b vf = *(const s4b*)&lV[r * 128 + (cl << 3) + ((quad & 1) << 2)];
        oacc[0][dt] = __builtin_amdgcn_mfma_f32_16x16x16bf16_1k(vf, pb[0], oacc[0][dt], 0, 0, 0);
        oacc[1][dt] = __builtin_amdgcn_mfma_f32_16x16x16bf16_1k(vf, pb[1], oacc[1][dt], 0, 0, 0);
      }
    }
    __syncthreads();
  }

  // epilogue: O^T col=q(l15), row=d(quad*4+r within dt-tile) -> O[b, q, h*64+d], 8B stores
  int b = bh >> 4, h = bh & 15;
  #pragma unroll
  for (int mi = 0; mi < 2; mi++) {
    float inv = 1.f / lst[mi];
    int qg = q0 + wave * 32 + mi * 16 + l15;
    size_t base = (((size_t)(b * S_TOT + qg)) << 10) + h * 64;
    #pragma unroll
    for (int dt = 0; dt < 4; dt++) {
      s4b o;
      #pragma unroll
      for (int r = 0; r < 4; r++) o[r] = (short)f2bf(oacc[mi][dt][r] * inv);
      *(s4b*)&O[base + dt * 16 + quad * 4] = o;
    }
  }
}

// ---------------- launch ----------------
extern "C" void kernel_launch(void* const* d_in, const int* in_sizes, int n_in,
                              void* d_out, int out_size, void* d_ws, size_t ws_size,
                              hipStream_t stream) {
  const float* x       = (const float*)d_in[0];
  const float* mod     = (const float*)d_in[1];
  const float* cond    = (const float*)d_in[2];
  const float* w_adaln = (const float*)d_in[3];
  const float* b_adaln = (const float*)d_in[4];
  const float* w_qkv   = (const float*)d_in[5];
  const float* b_qkv   = (const float*)d_in[6];
  const float* w_proj  = (const float*)d_in[7];
  const float* b_proj  = (const float*)d_in[8];
  const float* w_s1    = (const float*)d_in[9];
  const float* b_s1    = (const float*)d_in[10];
  const float* w_s2    = (const float*)d_in[11];
  const float* b_s2    = (const float*)d_in[12];
  const float* w_d1    = (const float*)d_in[13];
  const float* b_d1    = (const float*)d_in[14];
  const float* w_d2    = (const float*)d_in[15];
  const float* b_d2    = (const float*)d_in[16];

  float* outx = (float*)d_out;
  float* outc = outx + (size_t)2 * N_SEQ * C_DIM;

  char* w = (char*)d_ws;
  auto alloc = [&](size_t bytes) { char* p = w; w += (bytes + 255) & ~(size_t)255; return p; };
  float* m_ws  = (float*)alloc(12288 * 4);
  u16* wqkvT   = (u16*)alloc((size_t)3072 * 1024 * 2);
  u16* wprojT  = (u16*)alloc((size_t)1024 * 1024 * 2);
  u16* ws1T    = (u16*)alloc((size_t)4096 * 1024 * 2);
  u16* ws2T    = (u16*)alloc((size_t)4096 * 1024 * 2);
  u16* wd1T    = (u16*)alloc((size_t)4096 * 1024 * 2);
  u16* wd2T    = (u16*)alloc((size_t)4096 * 1024 * 2);
  u16* joint   = (u16*)alloc((size_t)4608 * 1024 * 2);   // also reused as attn_out
  u16* Qb      = (u16*)alloc((size_t)4718592 * 2);
  u16* Kb      = (u16*)alloc((size_t)4718592 * 2);
  u16* Vb      = (u16*)alloc((size_t)4718592 * 2);
  u16* Vtb     = (u16*)alloc((size_t)4718592 * 2);
  u16* h1x     = (u16*)alloc((size_t)4096 * 4096 * 2);
  u16* h1c     = (u16*)alloc((size_t)512 * 4096 * 2);
  u16* xln2 = Qb;       // alias: Q dead after flash
  u16* cln2 = Kb;       // alias: K dead after flash
  u16* attn_out = joint;

  size_t needed = (size_t)(w - (char*)d_ws);
  if (needed > ws_size) {  // distinctive failure mode: zero output
    hipMemsetAsync(d_out, 0, (size_t)out_size * 4, stream);
    return;
  }

  hipMemsetAsync(m_ws, 0, 12288 * 4, stream);
  adaln_mod<<<dim3(24, 2, 8), 256, 0, stream>>>(mod, w_adaln, m_ws);

  wtrans<<<dim3(96, 32), 256, 0, stream>>>(w_qkv, wqkvT, 1024, 3072);
  wtrans<<<dim3(32, 32), 256, 0, stream>>>(w_proj, wprojT, 1024, 1024);
  wtrans<<<dim3(128, 32), 256, 0, stream>>>(w_s1, ws1T, 1024, 4096);
  wtrans<<<dim3(32, 128), 256, 0, stream>>>(w_s2, ws2T, 4096, 1024);
  wtrans<<<dim3(128, 32), 256, 0, stream>>>(w_d1, wd1T, 1024, 4096);
  wtrans<<<dim3(32, 128), 256, 0, stream>>>(w_d2, wd2T, 4096, 1024);

  ln_mod1<<<4608, 256, 0, stream>>>(x, cond, m_ws, b_adaln, joint);

  gemm_k<0><<<dim3(24, 36), 256, 0, stream>>>(joint, wqkvT, b_qkv, 4608, 3072, 1024,
      nullptr, nullptr, nullptr, nullptr, nullptr, nullptr, Qb, Kb, Vb, nullptr, 0, 0);

  vtrans<<<dim3(36, 32), 256, 0, stream>>>(Vb, Vtb);
  flash_attn<<<dim3(18, 32), 256, 0, stream>>>(Qb, Kb, Vtb, attn_out);

  gemm_k<1><<<dim3(8, 36), 256, 0, stream>>>(attn_out, wprojT, b_proj, 4608, 1024, 1024,
      m_ws, b_adaln, x, cond, outx, outc, nullptr, nullptr, nullptr, nullptr, 0, 0);

  ln_mod2<<<4608, 256, 0, stream>>>(outx, outc, m_ws, b_adaln, xln2, cln2);

  gemm_k<2><<<dim3(32, 32), 256, 0, stream>>>(xln2, ws1T, b_s1, 4096, 4096, 1024,
      nullptr, nullptr, nullptr, nullptr, nullptr, nullptr, nullptr, nullptr, nullptr, h1x, 0, 0);
  gemm_k<4><<<dim3(8, 32), 256, 0, stream>>>(h1x, ws2T, b_s2, 4096, 1024, 4096,
      m_ws, b_adaln, nullptr, nullptr, outx, nullptr, nullptr, nullptr, nullptr, nullptr, 11, 5120);

  gemm_k<3><<<dim3(32, 4), 256, 0, stream>>>(cln2, wd1T, b_d1, 512, 4096, 1024,
      nullptr, nullptr, nullptr, nullptr, nullptr, nullptr, nullptr, nullptr, nullptr, h1c, 0, 0);
  gemm_k<4><<<dim3(8, 4), 256, 0, stream>>>(h1c, wd2T, b_d2, 512, 1024, 4096,
      m_ws, b_adaln, nullptr, nullptr, outc, nullptr, nullptr, nullptr, nullptr, nullptr, 8, 5120);
}

// Round 3
// 637.291 us; speedup vs baseline: 1.4281x; 1.0849x over previous
//
#include <hip/hip_runtime.h>

typedef unsigned short u16;
typedef __attribute__((ext_vector_type(8))) short short8;
typedef __attribute__((ext_vector_type(4))) short s4b;
typedef __attribute__((ext_vector_type(4))) float floatx4;

#define S_TOT 2304
#define N_SEQ 2048
#define T_SEQ 256
#define C_DIM 1024
#define NH 16
#define DH 64
#define SIX_C 6144

__device__ __forceinline__ u16 f2bf(float f) {
  union { float f; unsigned u; } v; v.f = f;
  unsigned r = (v.u + 0x7FFFu + ((v.u >> 16) & 1u)) >> 16;
  return (u16)r;
}
__device__ __forceinline__ float bf2f(u16 u) {
  union { unsigned u; float f; } v; v.u = ((unsigned)u) << 16; return v.f;
}
__device__ __forceinline__ unsigned fbits(float f) {
  union { float f; unsigned u; } v; v.f = f; return v.u;
}

__device__ __forceinline__ void async16(const void* g, void* l) {
  __builtin_amdgcn_global_load_lds((const __attribute__((address_space(1))) void*)g,
                                   (__attribute__((address_space(3))) void*)l, 16, 0, 0);
}

__device__ __forceinline__ floatx4 zero4() {
  floatx4 z; z[0] = 0.f; z[1] = 0.f; z[2] = 0.f; z[3] = 0.f; return z;
}

// ---------------- adaLN modulation: m = silu(mod) @ w_adaln (k-split, atomic) --------------
__global__ __launch_bounds__(256)
void adaln_mod(const float* __restrict__ mod, const float* __restrict__ w,
               float* __restrict__ m) {
  __shared__ float sm[128];
  int b = blockIdx.y, kz = blockIdx.z;
  int tid = threadIdx.x;
  if (tid < 128) {
    float v = mod[b * C_DIM + kz * 128 + tid];
    sm[tid] = v / (1.f + __expf(-v));
  }
  __syncthreads();
  int j = blockIdx.x * 256 + tid;
  const float* wp = w + (size_t)(kz * 128) * SIX_C + j;
  float acc = 0.f;
  #pragma unroll 8
  for (int k = 0; k < 128; k++) acc += sm[k] * wp[(size_t)k * SIX_C];
  atomicAdd(&m[b * SIX_C + j], acc);
}

// ---------------- fused weight transpose + cast: all 6 weights in one launch ----------------
__global__ __launch_bounds__(256)
void wtrans_all(const float* __restrict__ w0, const float* __restrict__ w1,
                const float* __restrict__ w2, const float* __restrict__ w3,
                const float* __restrict__ w4, const float* __restrict__ w5,
                u16* __restrict__ o0, u16* __restrict__ o1, u16* __restrict__ o2,
                u16* __restrict__ o3, u16* __restrict__ o4, u16* __restrict__ o5) {
  int bid = blockIdx.x;
  const float* W; u16* Wt; int K, N, bx, local;
  if (bid < 3072)       { W = w0; Wt = o0; K = 1024; N = 3072; bx = 96;  local = bid; }
  else if (bid < 4096)  { W = w1; Wt = o1; K = 1024; N = 1024; bx = 32;  local = bid - 3072; }
  else if (bid < 8192)  { W = w2; Wt = o2; K = 1024; N = 4096; bx = 128; local = bid - 4096; }
  else if (bid < 12288) { W = w3; Wt = o3; K = 4096; N = 1024; bx = 32;  local = bid - 8192; }
  else if (bid < 16384) { W = w4; Wt = o4; K = 1024; N = 4096; bx = 128; local = bid - 12288; }
  else                  { W = w5; Wt = o5; K = 4096; N = 1024; bx = 32;  local = bid - 16384; }
  int n0 = (local % bx) << 5, k0 = (local / bx) << 5;
  __shared__ float t[32][33];
  int tx = threadIdx.x & 31, ty = threadIdx.x >> 5;
  #pragma unroll
  for (int i = 0; i < 32; i += 8)
    t[ty + i][tx] = W[(size_t)(k0 + ty + i) * N + n0 + tx];
  __syncthreads();
  #pragma unroll
  for (int i = 0; i < 32; i += 8)
    Wt[(size_t)(n0 + ty + i) * K + k0 + tx] = f2bf(t[tx][ty + i]);
}

// ---------------- V[b,h,s,d] bf16 -> Vt[b,h,d,s] bf16 ----------------
__global__ __launch_bounds__(256)
void vtrans(const u16* __restrict__ V, u16* __restrict__ Vt) {
  __shared__ u16 t[64][65];
  int s0 = blockIdx.x << 6;
  int bh = blockIdx.y;
  const u16* src = V + (size_t)bh * S_TOT * DH;
  u16* dst = Vt + (size_t)bh * DH * S_TOT;
  int tid = threadIdx.x;
  #pragma unroll
  for (int i = 0; i < 16; i++) {
    int idx = tid + i * 256; int r = idx >> 6, c = idx & 63;
    t[r][c] = src[(size_t)(s0 + r) * DH + c];
  }
  __syncthreads();
  #pragma unroll
  for (int i = 0; i < 16; i++) {
    int idx = tid + i * 256; int r = idx >> 6, c = idx & 63;
    dst[(size_t)r * S_TOT + s0 + c] = t[c][r];
  }
}

// ---------------- LN + modulation -> bf16 (SHIFT_OFS selects msa/mlp params) ----------------
template<int SHIFT_OFS>
__global__ __launch_bounds__(256)
void ln_mod(const float* __restrict__ xin, const float* __restrict__ cin,
            const float* __restrict__ m, const float* __restrict__ ba,
            u16* __restrict__ xo, u16* __restrict__ co, u16* __restrict__ joint) {
  int row = blockIdx.x;
  int b = row / S_TOT, s = row - b * S_TOT;
  bool isx = (s < N_SEQ);
  size_t roff = isx ? (((size_t)(b * N_SEQ + s)) << 10)
                    : (((size_t)(b * T_SEQ + (s - N_SEQ))) << 10);
  const float* src = isx ? (xin + roff) : (cin + roff);
  int tid = threadIdx.x;
  float4 v = ((const float4*)src)[tid];
  float s1 = v.x + v.y + v.z + v.w;
  float s2 = v.x * v.x + v.y * v.y + v.z * v.z + v.w * v.w;
  #pragma unroll
  for (int o = 32; o; o >>= 1) { s1 += __shfl_xor(s1, o); s2 += __shfl_xor(s2, o); }
  __shared__ float red[8];
  int wv = tid >> 6, ln = tid & 63;
  if (ln == 0) { red[wv] = s1; red[4 + wv] = s2; }
  __syncthreads();
  s1 = red[0] + red[1] + red[2] + red[3];
  s2 = red[4] + red[5] + red[6] + red[7];
  float mu = s1 * (1.f / 1024.f);
  float var = s2 * (1.f / 1024.f) - mu * mu;
  float rstd = rsqrtf(var + 1e-6f);
  int c = tid << 2;
  const float* mb = m + b * SIX_C;
  float4 sc = *(const float4*)(mb + SHIFT_OFS + 1024 + c);
  float4 sb = *(const float4*)(ba + SHIFT_OFS + 1024 + c);
  float4 sh = *(const float4*)(mb + SHIFT_OFS + c);
  float4 hb = *(const float4*)(ba + SHIFT_OFS + c);
  float y0 = (v.x - mu) * rstd * (1.f + sc.x + sb.x) + sh.x + hb.x;
  float y1 = (v.y - mu) * rstd * (1.f + sc.y + sb.y) + sh.y + hb.y;
  float y2 = (v.z - mu) * rstd * (1.f + sc.z + sb.z) + sh.z + hb.z;
  float y3 = (v.w - mu) * rstd * (1.f + sc.w + sb.w) + sh.w + hb.w;
  unsigned long long o = (unsigned long long)f2bf(y0)
      | ((unsigned long long)f2bf(y1) << 16)
      | ((unsigned long long)f2bf(y2) << 32)
      | ((unsigned long long)f2bf(y3) << 48);
  u16* dst;
  if (SHIFT_OFS == 0) dst = joint + (((size_t)row) << 10);
  else dst = (isx ? xo : co) + roff;
  *(unsigned long long*)(dst + c) = o;
}

// ---------------- GEMM: C = A[M,K] @ Bt[N,K]^T, bf16 in, fp32 acc, mode epilogues -------
// MODE 0: qkv scatter  1: proj+residual+gate  2: gelu->bf16  3: silu->bf16
// MODE 4: atomicAdd(d_out, val*g)  (supports grid.z K-split; bias applied on z==0)
// MT: 128 or 64 (M-tile)
template<int MODE, int MT>
__global__ __launch_bounds__(256)
void gemm_k(const u16* __restrict__ A, const u16* __restrict__ Bt,
            const float* __restrict__ bias, int M, int N, int K,
            const float* __restrict__ mvec, const float* __restrict__ ba,
            const float* __restrict__ rx, const float* __restrict__ rc,
            float* __restrict__ ox, float* __restrict__ oc,
            u16* __restrict__ oq, u16* __restrict__ okd, u16* __restrict__ ov,
            u16* __restrict__ obf, int rshift, int gofs)
{
  __shared__ alignas(16) u16 lA[MT * 32];
  __shared__ alignas(16) u16 lB[128 * 32];
  int tid = threadIdx.x;
  int wave = tid >> 6, lane = tid & 63, quad = lane >> 4, l15 = lane & 15;
  int bx = blockIdx.x, by = blockIdx.y;
  const int MF = MT / 32;            // M-frags per wave (4 or 2)
  int wm = (wave >> 1) * (MT / 2), wn = (wave & 1) << 6;
  const u16* Ag = A + (size_t)(by * MT) * K;
  const u16* Bg = Bt + (size_t)(bx << 7) * K;
  floatx4 acc[MF][4];
  #pragma unroll
  for (int i = 0; i < MF; i++)
    #pragma unroll
    for (int j = 0; j < 4; j++) acc[i][j] = zero4();

  int kn = K / gridDim.z;
  int kbeg = blockIdx.z * kn, kend = kbeg + kn;

  for (int k0 = kbeg; k0 < kend; k0 += 32) {
    #pragma unroll
    for (int i = 0; i < MT / 64; i++) {
      int c = tid + (i << 8);
      async16(&Ag[(size_t)(c >> 2) * K + k0 + ((c & 3) << 3)], &lA[(size_t)c << 3]);
    }
    #pragma unroll
    for (int i = 0; i < 2; i++) {
      int c = tid + (i << 8);
      async16(&Bg[(size_t)(c >> 2) * K + k0 + ((c & 3) << 3)], &lB[(size_t)c << 3]);
    }
    __syncthreads();
    short8 af[MF], bfr[4];
    #pragma unroll
    for (int i = 0; i < MF; i++)
      af[i] = *(const short8*)&lA[(wm + (i << 4) + l15) * 32 + (quad << 3)];
    #pragma unroll
    for (int i = 0; i < 4; i++)
      bfr[i] = *(const short8*)&lB[(wn + (i << 4) + l15) * 32 + (quad << 3)];
    #pragma unroll
    for (int mi = 0; mi < MF; mi++)
      #pragma unroll
      for (int ni = 0; ni < 4; ni++)
        acc[mi][ni] = __builtin_amdgcn_mfma_f32_16x16x32_bf16(af[mi], bfr[ni], acc[mi][ni], 0, 0, 0);
    __syncthreads();
  }

  #pragma unroll
  for (int mi = 0; mi < MF; mi++) {
    #pragma unroll
    for (int r = 0; r < 4; r++) {
      int rg = by * MT + wm + (mi << 4) + (quad << 2) + r;
      if (MODE == 0) {
        int b = rg / S_TOT; int s = rg - b * S_TOT;
        #pragma unroll
        for (int ni = 0; ni < 4; ni++) {
          int col = (bx << 7) + wn + (ni << 4) + l15;
          float val = acc[mi][ni][r] + bias[col];
          int part = col >> 10, h = (col >> 6) & 15, d = col & 63;
          u16* dst = (part == 0) ? oq : (part == 1 ? okd : ov);
          dst[(((size_t)(b * NH + h)) * S_TOT + s) * DH + d] = f2bf(val);
        }
      } else if (MODE == 1) {
        int b = rg / S_TOT; int s = rg - b * S_TOT;
        #pragma unroll
        for (int ni = 0; ni < 4; ni++) {
          int col = (bx << 7) + wn + (ni << 4) + l15;
          float val = acc[mi][ni][r] + bias[col];
          float g = mvec[b * SIX_C + 2048 + col] + ba[2048 + col];
          if (s < N_SEQ) {
            size_t idx = (((size_t)(b * N_SEQ + s)) << 10) + col;
            ox[idx] = rx[idx] + val * g;
          } else {
            size_t idx = (((size_t)(b * T_SEQ + (s - N_SEQ))) << 10) + col;
            oc[idx] = rc[idx] + val * g;
          }
        }
      } else if (MODE == 2) {
        #pragma unroll
        for (int ni = 0; ni < 4; ni++) {
          int col = (bx << 7) + wn + (ni << 4) + l15;
          float t = acc[mi][ni][r] + bias[col];
          float u = 0.7978845608028654f * (t + 0.044715f * t * t * t);
          float e = __expf(2.f * u);
          float th = 1.f - 2.f / (e + 1.f);
          obf[(size_t)rg * N + col] = f2bf(0.5f * t * (1.f + th));
        }
      } else if (MODE == 3) {
        #pragma unroll
        for (int ni = 0; ni < 4; ni++) {
          int col = (bx << 7) + wn + (ni << 4) + l15;
          float t = acc[mi][ni][r] + bias[col];
          obf[(size_t)rg * N + col] = f2bf(t / (1.f + __expf(-t)));
        }
      } else {  // MODE 4
        int b = rg >> rshift;
        #pragma unroll
        for (int ni = 0; ni < 4; ni++) {
          int col = (bx << 7) + wn + (ni << 4) + l15;
          float val = acc[mi][ni][r] + (blockIdx.z == 0 ? bias[col] : 0.f);
          float g = mvec[b * SIX_C + gofs + col] + ba[gofs + col];
          size_t idx = (((size_t)rg) << 10) + col;
          atomicAdd(&ox[idx], val * g);
        }
      }
    }
  }
}

// ---------------- flash attention (S^T trick; 2 waves / 64 q-rows per block) -------
__global__ __launch_bounds__(128)
void flash_attn(const u16* __restrict__ Q, const u16* __restrict__ K,
                const u16* __restrict__ V, u16* __restrict__ O) {
  __shared__ alignas(16) u16 lK[128 * 64];   // [s][d], chunk-xor-swizzled
  __shared__ alignas(16) u16 lV[64 * 128];   // [d][s], chunk-xor-swizzled
  int tid = threadIdx.x;
  int wave = tid >> 6, lane = tid & 63, quad = lane >> 4, l15 = lane & 15;
  int q0 = blockIdx.x << 6;
  int bh = blockIdx.y;
  const u16* Qb = Q + (size_t)bh * S_TOT * DH;
  const u16* Kb = K + (size_t)bh * S_TOT * DH;
  const u16* Vb = V + (size_t)bh * DH * S_TOT;

  // Q fragments, pre-scaled by 1/8. B-layout for x32 QK^T: n=l15=q, k=quad*8+j.
  short8 qf[2][2];
  #pragma unroll
  for (int mi = 0; mi < 2; mi++) {
    const u16* qrow = Qb + (size_t)(q0 + wave * 32 + mi * 16 + l15) * DH;
    #pragma unroll
    for (int kd = 0; kd < 2; kd++) {
      short8 raw = *(const short8*)&qrow[kd * 32 + quad * 8];
      short8 sc;
      #pragma unroll
      for (int j = 0; j < 8; j++) sc[j] = (short)f2bf(bf2f((u16)raw[j]) * 0.125f);
      qf[mi][kd] = sc;
    }
  }

  floatx4 oacc[2][4];   // O^T acc: col=q, row=d
  #pragma unroll
  for (int mi = 0; mi < 2; mi++)
    #pragma unroll
    for (int dt = 0; dt < 4; dt++) oacc[mi][dt] = zero4();
  float mst[2] = {-1e30f, -1e30f}, lst[2] = {0.f, 0.f};

  for (int kv0 = 0; kv0 < S_TOT; kv0 += 128) {
    #pragma unroll
    for (int i = 0; i < 8; i++) {
      int ci = tid + (i << 7);
      int rK = ci >> 3, clK = ci & 7;
      int cgK = clK ^ (rK & 7);
      async16(&Kb[(size_t)(kv0 + rK) * DH + (cgK << 3)], &lK[(size_t)ci << 3]);
      int rV = ci >> 4, clV = ci & 15;
      int cgV = (clV & 8) | ((clV ^ (rV & 7)) & 7);
      async16(&Vb[(size_t)rV * S_TOT + kv0 + (cgV << 3)], &lV[(size_t)ci << 3]);
    }
    __syncthreads();

    // S^T: sacc[mi][si]; s = si*16 + quad*4 + r, q = l15
    floatx4 sacc[2][8];
    #pragma unroll
    for (int mi = 0; mi < 2; mi++)
      #pragma unroll
      for (int si = 0; si < 8; si++) sacc[mi][si] = zero4();
    #pragma unroll
    for (int si = 0; si < 8; si++) {
      int r = si * 16 + l15;
      #pragma unroll
      for (int kd = 0; kd < 2; kd++) {
        int c = (kd << 2) + quad;
        int cl = c ^ (r & 7);
        short8 kf = *(const short8*)&lK[r * 64 + (cl << 3)];
        sacc[0][si] = __builtin_amdgcn_mfma_f32_16x16x32_bf16(kf, qf[0][kd], sacc[0][si], 0, 0, 0);
        sacc[1][si] = __builtin_amdgcn_mfma_f32_16x16x32_bf16(kf, qf[1][kd], sacc[1][si], 0, 0, 0);
      }
    }

    // online softmax (lane-local + 2 shuffles per reduction)
    #pragma unroll
    for (int mi = 0; mi < 2; mi++) {
      float rm = -1e30f;
      #pragma unroll
      for (int si = 0; si < 8; si++)
        #pragma unroll
        for (int r = 0; r < 4; r++) rm = fmaxf(rm, sacc[mi][si][r]);
      rm = fmaxf(rm, __shfl_xor(rm, 16));
      rm = fmaxf(rm, __shfl_xor(rm, 32));
      float mnew = fmaxf(mst[mi], rm);
      float al = __expf(mst[mi] - mnew);
      mst[mi] = mnew;
      float rs = 0.f;
      #pragma unroll
      for (int si = 0; si < 8; si++)
        #pragma unroll
        for (int r = 0; r < 4; r++) {
          float p = __expf(sacc[mi][si][r] - mnew);
          sacc[mi][si][r] = p;
          rs += p;
        }
      rs += __shfl_xor(rs, 16);
      rs += __shfl_xor(rs, 32);
      lst[mi] = lst[mi] * al + rs;
      #pragma unroll
      for (int dt = 0; dt < 4; dt++)
        #pragma unroll
        for (int r = 0; r < 4; r++) oacc[mi][dt][r] *= al;
    }

    // O^T += V^T · P^T ; P packed lane-locally via v_perm (truncate to bf16)
    #pragma unroll
    for (int si = 0; si < 8; si++) {
      s4b pb[2];
      #pragma unroll
      for (int mi = 0; mi < 2; mi++) {
        union { s4b v; unsigned u[2]; } p;
        p.u[0] = __builtin_amdgcn_perm(fbits(sacc[mi][si][1]), fbits(sacc[mi][si][0]), 0x07060302u);
        p.u[1] = __builtin_amdgcn_perm(fbits(sacc[mi][si][3]), fbits(sacc[mi][si][2]), 0x07060302u);
        pb[mi] = p.v;
      }
      #pragma unroll
      for (int dt = 0; dt < 4; dt++) {
        int r = dt * 16 + l15;
        int c = (si << 1) + (quad >> 1);
        int cl = (c & 8) | ((c ^ (r & 7)) & 7);
        s4b vf = *(const s4b*)&lV[r * 128 + (cl << 3) + ((quad & 1) << 2)];
        oacc[0][dt] = __builtin_amdgcn_mfma_f32_16x16x16bf16_1k(vf, pb[0], oacc[0][dt], 0, 0, 0);
        oacc[1][dt] = __builtin_amdgcn_mfma_f32_16x16x16bf16_1k(vf, pb[1], oacc[1][dt], 0, 0, 0);
      }
    }
    __syncthreads();
  }

  int b = bh >> 4, h = bh & 15;
  #pragma unroll
  for (int mi = 0; mi < 2; mi++) {
    float inv = 1.f / lst[mi];
    int qg = q0 + wave * 32 + mi * 16 + l15;
    size_t base = (((size_t)(b * S_TOT + qg)) << 10) + h * 64;
    #pragma unroll
    for (int dt = 0; dt < 4; dt++) {
      s4b o;
      #pragma unroll
      for (int r = 0; r < 4; r++) o[r] = (short)f2bf(oacc[mi][dt][r] * inv);
      *(s4b*)&O[base + dt * 16 + quad * 4] = o;
    }
  }
}

// ---------------- launch ----------------
extern "C" void kernel_launch(void* const* d_in, const int* in_sizes, int n_in,
                              void* d_out, int out_size, void* d_ws, size_t ws_size,
                              hipStream_t stream) {
  const float* x       = (const float*)d_in[0];
  const float* mod     = (const float*)d_in[1];
  const float* cond    = (const float*)d_in[2];
  const float* w_adaln = (const float*)d_in[3];
  const float* b_adaln = (const float*)d_in[4];
  const float* w_qkv   = (const float*)d_in[5];
  const float* b_qkv   = (const float*)d_in[6];
  const float* w_proj  = (const float*)d_in[7];
  const float* b_proj  = (const float*)d_in[8];
  const float* w_s1    = (const float*)d_in[9];
  const float* b_s1    = (const float*)d_in[10];
  const float* w_s2    = (const float*)d_in[11];
  const float* b_s2    = (const float*)d_in[12];
  const float* w_d1    = (const float*)d_in[13];
  const float* b_d1    = (const float*)d_in[14];
  const float* w_d2    = (const float*)d_in[15];
  const float* b_d2    = (const float*)d_in[16];

  float* outx = (float*)d_out;
  float* outc = outx + (size_t)2 * N_SEQ * C_DIM;

  char* w = (char*)d_ws;
  auto alloc = [&](size_t bytes) { char* p = w; w += (bytes + 255) & ~(size_t)255; return p; };
  float* m_ws  = (float*)alloc(12288 * 4);
  u16* wqkvT   = (u16*)alloc((size_t)3072 * 1024 * 2);
  u16* wprojT  = (u16*)alloc((size_t)1024 * 1024 * 2);
  u16* ws1T    = (u16*)alloc((size_t)4096 * 1024 * 2);
  u16* ws2T    = (u16*)alloc((size_t)4096 * 1024 * 2);
  u16* wd1T    = (u16*)alloc((size_t)4096 * 1024 * 2);
  u16* wd2T    = (u16*)alloc((size_t)4096 * 1024 * 2);
  u16* joint   = (u16*)alloc((size_t)4608 * 1024 * 2);   // reused as attn_out
  u16* Qb      = (u16*)alloc((size_t)4718592 * 2);
  u16* Kb      = (u16*)alloc((size_t)4718592 * 2);
  u16* Vb      = (u16*)alloc((size_t)4718592 * 2);
  u16* Vtb     = (u16*)alloc((size_t)4718592 * 2);
  u16* h1x     = (u16*)alloc((size_t)4096 * 4096 * 2);
  u16* h1c     = (u16*)alloc((size_t)512 * 4096 * 2);
  u16* xln2 = Qb;       // alias: Q dead after flash
  u16* cln2 = Kb;       // alias: K dead after flash
  u16* attn_out = joint;

  size_t needed = (size_t)(w - (char*)d_ws);
  if (needed > ws_size) {
    hipMemsetAsync(d_out, 0, (size_t)out_size * 4, stream);
    return;
  }

  hipMemsetAsync(m_ws, 0, 12288 * 4, stream);
  adaln_mod<<<dim3(24, 2, 8), 256, 0, stream>>>(mod, w_adaln, m_ws);

  wtrans_all<<<20480, 256, 0, stream>>>(w_qkv, w_proj, w_s1, w_s2, w_d1, w_d2,
                                        wqkvT, wprojT, ws1T, ws2T, wd1T, wd2T);

  ln_mod<0><<<4608, 256, 0, stream>>>(x, cond, m_ws, b_adaln, nullptr, nullptr, joint);

  gemm_k<0, 128><<<dim3(24, 36), 256, 0, stream>>>(joint, wqkvT, b_qkv, 4608, 3072, 1024,
      nullptr, nullptr, nullptr, nullptr, nullptr, nullptr, Qb, Kb, Vb, nullptr, 0, 0);

  vtrans<<<dim3(36, 32), 256, 0, stream>>>(Vb, Vtb);
  flash_attn<<<dim3(36, 32), 128, 0, stream>>>(Qb, Kb, Vtb, attn_out);

  gemm_k<1, 128><<<dim3(8, 36), 256, 0, stream>>>(attn_out, wprojT, b_proj, 4608, 1024, 1024,
      m_ws, b_adaln, x, cond, outx, outc, nullptr, nullptr, nullptr, nullptr, 0, 0);

  ln_mod<3072><<<4608, 256, 0, stream>>>(outx, outc, m_ws, b_adaln, xln2, cln2, nullptr);

  gemm_k<2, 128><<<dim3(32, 32), 256, 0, stream>>>(xln2, ws1T, b_s1, 4096, 4096, 1024,
      nullptr, nullptr, nullptr, nullptr, nullptr, nullptr, nullptr, nullptr, nullptr, h1x, 0, 0);
  gemm_k<4, 128><<<dim3(8, 32, 2), 256, 0, stream>>>(h1x, ws2T, b_s2, 4096, 1024, 4096,
      m_ws, b_adaln, nullptr, nullptr, outx, nullptr, nullptr, nullptr, nullptr, nullptr, 11, 5120);

  gemm_k<3, 64><<<dim3(32, 8), 256, 0, stream>>>(cln2, wd1T, b_d1, 512, 4096, 1024,
      nullptr, nullptr, nullptr, nullptr, nullptr, nullptr, nullptr, nullptr, nullptr, h1c, 0, 0);
  gemm_k<4, 64><<<dim3(8, 8, 4), 256, 0, stream>>>(h1c, wd2T, b_d2, 512, 1024, 4096,
      m_ws, b_adaln, nullptr, nullptr, outc, nullptr, nullptr, nullptr, nullptr, nullptr, 8, 5120);
}

// Round 4
// 532.190 us; speedup vs baseline: 1.7102x; 1.1975x over previous
//
#include <hip/hip_runtime.h>

typedef unsigned short u16;
typedef __attribute__((ext_vector_type(8))) short short8;
typedef __attribute__((ext_vector_type(4))) short s4b;
typedef __attribute__((ext_vector_type(4))) float floatx4;

#define S_TOT 2304
#define N_SEQ 2048
#define T_SEQ 256
#define C_DIM 1024
#define NH 16
#define DH 64
#define SIX_C 6144

__device__ __forceinline__ u16 f2bf(float f) {
  union { float f; unsigned u; } v; v.f = f;
  unsigned r = (v.u + 0x7FFFu + ((v.u >> 16) & 1u)) >> 16;
  return (u16)r;
}
__device__ __forceinline__ float bf2f(u16 u) {
  union { unsigned u; float f; } v; v.u = ((unsigned)u) << 16; return v.f;
}
__device__ __forceinline__ unsigned fbits(float f) {
  union { float f; unsigned u; } v; v.f = f; return v.u;
}

__device__ __forceinline__ void async16(const void* g, void* l) {
  __builtin_amdgcn_global_load_lds((const __attribute__((address_space(1))) void*)g,
                                   (__attribute__((address_space(3))) void*)l, 16, 0, 0);
}

__device__ __forceinline__ floatx4 zero4() {
  floatx4 z; z[0] = 0.f; z[1] = 0.f; z[2] = 0.f; z[3] = 0.f; return z;
}

// ---------------- adaLN modulation: m = silu(mod) @ w_adaln (k-split, atomic) --------------
__global__ __launch_bounds__(256)
void adaln_mod(const float* __restrict__ mod, const float* __restrict__ w,
               float* __restrict__ m) {
  __shared__ float sm[128];
  int b = blockIdx.y, kz = blockIdx.z;
  int tid = threadIdx.x;
  if (tid < 128) {
    float v = mod[b * C_DIM + kz * 128 + tid];
    sm[tid] = v / (1.f + __expf(-v));
  }
  __syncthreads();
  int j = blockIdx.x * 256 + tid;
  const float* wp = w + (size_t)(kz * 128) * SIX_C + j;
  float acc = 0.f;
  #pragma unroll 8
  for (int k = 0; k < 128; k++) acc += sm[k] * wp[(size_t)k * SIX_C];
  atomicAdd(&m[b * SIX_C + j], acc);
}

// ---------------- fused weight transpose + cast ----------------
__global__ __launch_bounds__(256)
void wtrans_all(const float* __restrict__ w0, const float* __restrict__ w1,
                const float* __restrict__ w2, const float* __restrict__ w3,
                const float* __restrict__ w4, const float* __restrict__ w5,
                u16* __restrict__ o0, u16* __restrict__ o1, u16* __restrict__ o2,
                u16* __restrict__ o3, u16* __restrict__ o4, u16* __restrict__ o5) {
  int bid = blockIdx.x;
  const float* W; u16* Wt; int K, N, bx, local;
  if (bid < 3072)       { W = w0; Wt = o0; K = 1024; N = 3072; bx = 96;  local = bid; }
  else if (bid < 4096)  { W = w1; Wt = o1; K = 1024; N = 1024; bx = 32;  local = bid - 3072; }
  else if (bid < 8192)  { W = w2; Wt = o2; K = 1024; N = 4096; bx = 128; local = bid - 4096; }
  else if (bid < 12288) { W = w3; Wt = o3; K = 4096; N = 1024; bx = 32;  local = bid - 8192; }
  else if (bid < 16384) { W = w4; Wt = o4; K = 1024; N = 4096; bx = 128; local = bid - 12288; }
  else                  { W = w5; Wt = o5; K = 4096; N = 1024; bx = 32;  local = bid - 16384; }
  int n0 = (local % bx) << 5, k0 = (local / bx) << 5;
  __shared__ float t[32][33];
  int tx = threadIdx.x & 31, ty = threadIdx.x >> 5;
  #pragma unroll
  for (int i = 0; i < 32; i += 8)
    t[ty + i][tx] = W[(size_t)(k0 + ty + i) * N + n0 + tx];
  __syncthreads();
  #pragma unroll
  for (int i = 0; i < 32; i += 8)
    Wt[(size_t)(n0 + ty + i) * K + k0 + tx] = f2bf(t[tx][ty + i]);
}

// ---------------- V[b,h,s,d] bf16 -> Vt[b,h,d,s] bf16 ----------------
__global__ __launch_bounds__(256)
void vtrans(const u16* __restrict__ V, u16* __restrict__ Vt) {
  __shared__ u16 t[64][65];
  int s0 = blockIdx.x << 6;
  int bh = blockIdx.y;
  const u16* src = V + (size_t)bh * S_TOT * DH;
  u16* dst = Vt + (size_t)bh * DH * S_TOT;
  int tid = threadIdx.x;
  #pragma unroll
  for (int i = 0; i < 16; i++) {
    int idx = tid + i * 256; int r = idx >> 6, c = idx & 63;
    t[r][c] = src[(size_t)(s0 + r) * DH + c];
  }
  __syncthreads();
  #pragma unroll
  for (int i = 0; i < 16; i++) {
    int idx = tid + i * 256; int r = idx >> 6, c = idx & 63;
    dst[(size_t)r * S_TOT + s0 + c] = t[c][r];
  }
}

// ---------------- LN + modulation -> bf16 ----------------
template<int SHIFT_OFS>
__global__ __launch_bounds__(256)
void ln_mod(const float* __restrict__ xin, const float* __restrict__ cin,
            const float* __restrict__ m, const float* __restrict__ ba,
            u16* __restrict__ xo, u16* __restrict__ co, u16* __restrict__ joint) {
  int row = blockIdx.x;
  int b = row / S_TOT, s = row - b * S_TOT;
  bool isx = (s < N_SEQ);
  size_t roff = isx ? (((size_t)(b * N_SEQ + s)) << 10)
                    : (((size_t)(b * T_SEQ + (s - N_SEQ))) << 10);
  const float* src = isx ? (xin + roff) : (cin + roff);
  int tid = threadIdx.x;
  float4 v = ((const float4*)src)[tid];
  float s1 = v.x + v.y + v.z + v.w;
  float s2 = v.x * v.x + v.y * v.y + v.z * v.z + v.w * v.w;
  #pragma unroll
  for (int o = 32; o; o >>= 1) { s1 += __shfl_xor(s1, o); s2 += __shfl_xor(s2, o); }
  __shared__ float red[8];
  int wv = tid >> 6, ln = tid & 63;
  if (ln == 0) { red[wv] = s1; red[4 + wv] = s2; }
  __syncthreads();
  s1 = red[0] + red[1] + red[2] + red[3];
  s2 = red[4] + red[5] + red[6] + red[7];
  float mu = s1 * (1.f / 1024.f);
  float var = s2 * (1.f / 1024.f) - mu * mu;
  float rstd = rsqrtf(var + 1e-6f);
  int c = tid << 2;
  const float* mb = m + b * SIX_C;
  float4 sc = *(const float4*)(mb + SHIFT_OFS + 1024 + c);
  float4 sb = *(const float4*)(ba + SHIFT_OFS + 1024 + c);
  float4 sh = *(const float4*)(mb + SHIFT_OFS + c);
  float4 hb = *(const float4*)(ba + SHIFT_OFS + c);
  float y0 = (v.x - mu) * rstd * (1.f + sc.x + sb.x) + sh.x + hb.x;
  float y1 = (v.y - mu) * rstd * (1.f + sc.y + sb.y) + sh.y + hb.y;
  float y2 = (v.z - mu) * rstd * (1.f + sc.z + sb.z) + sh.z + hb.z;
  float y3 = (v.w - mu) * rstd * (1.f + sc.w + sb.w) + sh.w + hb.w;
  unsigned long long o = (unsigned long long)f2bf(y0)
      | ((unsigned long long)f2bf(y1) << 16)
      | ((unsigned long long)f2bf(y2) << 32)
      | ((unsigned long long)f2bf(y3) << 48);
  u16* dst;
  if (SHIFT_OFS == 0) dst = joint + (((size_t)row) << 10);
  else dst = (isx ? xo : co) + roff;
  *(unsigned long long*)(dst + c) = o;
}

// ---------------- GEMM: C = A[M,K] @ Bt[N,K]^T. MODE 0: qkv scatter, MODE 1: proj+res+gate
template<int MODE, int MT>
__global__ __launch_bounds__(256)
void gemm_k(const u16* __restrict__ A, const u16* __restrict__ Bt,
            const float* __restrict__ bias, int K,
            const float* __restrict__ mvec, const float* __restrict__ ba,
            const float* __restrict__ rx, const float* __restrict__ rc,
            float* __restrict__ ox, float* __restrict__ oc,
            u16* __restrict__ oq, u16* __restrict__ okd, u16* __restrict__ ov)
{
  __shared__ alignas(16) u16 lA[MT * 32];
  __shared__ alignas(16) u16 lB[128 * 32];
  int tid = threadIdx.x;
  int wave = tid >> 6, lane = tid & 63, quad = lane >> 4, l15 = lane & 15;
  int bx = blockIdx.x, by = blockIdx.y;
  const int MF = MT / 32;
  int wm = (wave >> 1) * (MT / 2), wn = (wave & 1) << 6;
  const u16* Ag = A + (size_t)(by * MT) * K;
  const u16* Bg = Bt + (size_t)(bx << 7) * K;
  floatx4 acc[MF][4];
  #pragma unroll
  for (int i = 0; i < MF; i++)
    #pragma unroll
    for (int j = 0; j < 4; j++) acc[i][j] = zero4();

  for (int k0 = 0; k0 < K; k0 += 32) {
    #pragma unroll
    for (int i = 0; i < MT / 64; i++) {
      int c = tid + (i << 8);
      async16(&Ag[(size_t)(c >> 2) * K + k0 + ((c & 3) << 3)], &lA[(size_t)c << 3]);
    }
    #pragma unroll
    for (int i = 0; i < 2; i++) {
      int c = tid + (i << 8);
      async16(&Bg[(size_t)(c >> 2) * K + k0 + ((c & 3) << 3)], &lB[(size_t)c << 3]);
    }
    __syncthreads();
    short8 af[MF], bfr[4];
    #pragma unroll
    for (int i = 0; i < MF; i++)
      af[i] = *(const short8*)&lA[(wm + (i << 4) + l15) * 32 + (quad << 3)];
    #pragma unroll
    for (int i = 0; i < 4; i++)
      bfr[i] = *(const short8*)&lB[(wn + (i << 4) + l15) * 32 + (quad << 3)];
    #pragma unroll
    for (int mi = 0; mi < MF; mi++)
      #pragma unroll
      for (int ni = 0; ni < 4; ni++)
        acc[mi][ni] = __builtin_amdgcn_mfma_f32_16x16x32_bf16(af[mi], bfr[ni], acc[mi][ni], 0, 0, 0);
    __syncthreads();
  }

  #pragma unroll
  for (int mi = 0; mi < MF; mi++) {
    #pragma unroll
    for (int r = 0; r < 4; r++) {
      int rg = by * MT + wm + (mi << 4) + (quad << 2) + r;
      int b = rg / S_TOT; int s = rg - b * S_TOT;
      if (MODE == 0) {
        #pragma unroll
        for (int ni = 0; ni < 4; ni++) {
          int col = (bx << 7) + wn + (ni << 4) + l15;
          float val = acc[mi][ni][r] + bias[col];
          int part = col >> 10, h = (col >> 6) & 15, d = col & 63;
          u16* dst = (part == 0) ? oq : (part == 1 ? okd : ov);
          dst[(((size_t)(b * NH + h)) * S_TOT + s) * DH + d] = f2bf(val);
        }
      } else {
        #pragma unroll
        for (int ni = 0; ni < 4; ni++) {
          int col = (bx << 7) + wn + (ni << 4) + l15;
          float val = acc[mi][ni][r] + bias[col];
          float g = mvec[b * SIX_C + 2048 + col] + ba[2048 + col];
          if (s < N_SEQ) {
            size_t idx = (((size_t)(b * N_SEQ + s)) << 10) + col;
            ox[idx] = rx[idx] + val * g;
          } else {
            size_t idx = (((size_t)(b * T_SEQ + (s - N_SEQ))) << 10) + col;
            oc[idx] = rc[idx] + val * g;
          }
        }
      }
    }
  }
}

// ---------------- fused MLP layer 1: [xln2;cln2] @ {ws1|wd1} + gelu|silu -> h1 ----------
__global__ __launch_bounds__(256)
void mlp1(const u16* __restrict__ Ax, const u16* __restrict__ Ac,
          const u16* __restrict__ Bx, const u16* __restrict__ Bc,
          const float* __restrict__ biasx, const float* __restrict__ biasc,
          u16* __restrict__ h1) {
  bool isx = (blockIdx.y < 32);
  const u16* A = isx ? (Ax + (size_t)(blockIdx.y << 7) * 1024)
                     : (Ac + (size_t)((blockIdx.y - 32) << 7) * 1024);
  const u16* Bt = isx ? Bx : Bc;
  const float* bias = isx ? biasx : biasc;
  const int K = 1024;
  __shared__ alignas(16) u16 lA[128 * 32];
  __shared__ alignas(16) u16 lB[128 * 32];
  int tid = threadIdx.x;
  int wave = tid >> 6, lane = tid & 63, quad = lane >> 4, l15 = lane & 15;
  int bx = blockIdx.x;
  int wm = (wave >> 1) << 6, wn = (wave & 1) << 6;
  const u16* Bg = Bt + (size_t)(bx << 7) * K;
  floatx4 acc[4][4];
  #pragma unroll
  for (int i = 0; i < 4; i++)
    #pragma unroll
    for (int j = 0; j < 4; j++) acc[i][j] = zero4();

  for (int k0 = 0; k0 < K; k0 += 32) {
    #pragma unroll
    for (int i = 0; i < 2; i++) {
      int c = tid + (i << 8);
      async16(&A[(size_t)(c >> 2) * K + k0 + ((c & 3) << 3)], &lA[(size_t)c << 3]);
      async16(&Bg[(size_t)(c >> 2) * K + k0 + ((c & 3) << 3)], &lB[(size_t)c << 3]);
    }
    __syncthreads();
    short8 af[4], bfr[4];
    #pragma unroll
    for (int i = 0; i < 4; i++) {
      af[i]  = *(const short8*)&lA[(wm + (i << 4) + l15) * 32 + (quad << 3)];
      bfr[i] = *(const short8*)&lB[(wn + (i << 4) + l15) * 32 + (quad << 3)];
    }
    #pragma unroll
    for (int mi = 0; mi < 4; mi++)
      #pragma unroll
      for (int ni = 0; ni < 4; ni++)
        acc[mi][ni] = __builtin_amdgcn_mfma_f32_16x16x32_bf16(af[mi], bfr[ni], acc[mi][ni], 0, 0, 0);
    __syncthreads();
  }

  #pragma unroll
  for (int mi = 0; mi < 4; mi++) {
    #pragma unroll
    for (int r = 0; r < 4; r++) {
      int rg = (blockIdx.y << 7) + wm + (mi << 4) + (quad << 2) + r;
      #pragma unroll
      for (int ni = 0; ni < 4; ni++) {
        int col = (bx << 7) + wn + (ni << 4) + l15;
        float t = acc[mi][ni][r] + bias[col];
        float act;
        if (isx) {
          float u = 0.7978845608028654f * (t + 0.044715f * t * t * t);
          float e = __expf(2.f * u);
          act = 0.5f * t * (1.f + (1.f - 2.f / (e + 1.f)));
        } else {
          act = t / (1.f + __expf(-t));
        }
        h1[(size_t)rg * 4096 + col] = f2bf(act);
      }
    }
  }
}

// ---------------- fused MLP layer 2 (K-split z=2): h1 @ {ws2|wd2}, atomic += val*g --------
__global__ __launch_bounds__(256)
void mlp2(const u16* __restrict__ h1,
          const u16* __restrict__ Bx, const u16* __restrict__ Bc,
          const float* __restrict__ biasx, const float* __restrict__ biasc,
          const float* __restrict__ mvec, const float* __restrict__ ba,
          float* __restrict__ outx, float* __restrict__ outc) {
  bool isx = (blockIdx.y < 32);
  const u16* A = h1 + (size_t)(blockIdx.y << 7) * 4096;
  const u16* Bt = isx ? Bx : Bc;
  const float* bias = isx ? biasx : biasc;
  const int K = 4096;
  __shared__ alignas(16) u16 lA[128 * 32];
  __shared__ alignas(16) u16 lB[128 * 32];
  int tid = threadIdx.x;
  int wave = tid >> 6, lane = tid & 63, quad = lane >> 4, l15 = lane & 15;
  int bx = blockIdx.x;
  int wm = (wave >> 1) << 6, wn = (wave & 1) << 6;
  const u16* Bg = Bt + (size_t)(bx << 7) * K;
  floatx4 acc[4][4];
  #pragma unroll
  for (int i = 0; i < 4; i++)
    #pragma unroll
    for (int j = 0; j < 4; j++) acc[i][j] = zero4();

  int kn = K >> 1;
  int kbeg = blockIdx.z * kn, kend = kbeg + kn;
  for (int k0 = kbeg; k0 < kend; k0 += 32) {
    #pragma unroll
    for (int i = 0; i < 2; i++) {
      int c = tid + (i << 8);
      async16(&A[(size_t)(c >> 2) * K + k0 + ((c & 3) << 3)], &lA[(size_t)c << 3]);
      async16(&Bg[(size_t)(c >> 2) * K + k0 + ((c & 3) << 3)], &lB[(size_t)c << 3]);
    }
    __syncthreads();
    short8 af[4], bfr[4];
    #pragma unroll
    for (int i = 0; i < 4; i++) {
      af[i]  = *(const short8*)&lA[(wm + (i << 4) + l15) * 32 + (quad << 3)];
      bfr[i] = *(const short8*)&lB[(wn + (i << 4) + l15) * 32 + (quad << 3)];
    }
    #pragma unroll
    for (int mi = 0; mi < 4; mi++)
      #pragma unroll
      for (int ni = 0; ni < 4; ni++)
        acc[mi][ni] = __builtin_amdgcn_mfma_f32_16x16x32_bf16(af[mi], bfr[ni], acc[mi][ni], 0, 0, 0);
    __syncthreads();
  }

  #pragma unroll
  for (int mi = 0; mi < 4; mi++) {
    #pragma unroll
    for (int r = 0; r < 4; r++) {
      int rg = (blockIdx.y << 7) + wm + (mi << 4) + (quad << 2) + r;
      int rl = isx ? rg : (rg - 4096);
      int b = isx ? (rg >> 11) : (rl >> 8);
      float* dst = isx ? outx : outc;
      #pragma unroll
      for (int ni = 0; ni < 4; ni++) {
        int col = (bx << 7) + wn + (ni << 4) + l15;
        float val = acc[mi][ni][r] + (blockIdx.z == 0 ? bias[col] : 0.f);
        float g = mvec[b * SIX_C + 5120 + col] + ba[5120 + col];
        atomicAdd(&dst[(((size_t)rl) << 10) + col], val * g);
      }
    }
  }
}

// ---------------- flash attention (S^T trick; 4 waves/128 q-rows; KV-split z=3) -------
__global__ __launch_bounds__(256)
void flash_attn(const u16* __restrict__ Q, const u16* __restrict__ K,
                const u16* __restrict__ V, u16* __restrict__ Op,
                float2* __restrict__ ml) {
  __shared__ alignas(16) u16 lK[128 * 64];
  __shared__ alignas(16) u16 lV[64 * 128];
  int tid = threadIdx.x;
  int wave = tid >> 6, lane = tid & 63, quad = lane >> 4, l15 = lane & 15;
  int q0 = blockIdx.x << 7;
  int bh = blockIdx.y;
  int z = blockIdx.z;
  const u16* Qb = Q + (size_t)bh * S_TOT * DH;
  const u16* Kb = K + (size_t)bh * S_TOT * DH;
  const u16* Vb = V + (size_t)bh * DH * S_TOT;

  short8 qf[2][2];
  #pragma unroll
  for (int mi = 0; mi < 2; mi++) {
    const u16* qrow = Qb + (size_t)(q0 + wave * 32 + mi * 16 + l15) * DH;
    #pragma unroll
    for (int kd = 0; kd < 2; kd++) {
      short8 raw = *(const short8*)&qrow[kd * 32 + quad * 8];
      short8 sc;
      #pragma unroll
      for (int j = 0; j < 8; j++) sc[j] = (short)f2bf(bf2f((u16)raw[j]) * 0.125f);
      qf[mi][kd] = sc;
    }
  }

  floatx4 oacc[2][4];
  #pragma unroll
  for (int mi = 0; mi < 2; mi++)
    #pragma unroll
    for (int dt = 0; dt < 4; dt++) oacc[mi][dt] = zero4();
  float mst[2] = {-1e30f, -1e30f}, lst[2] = {0.f, 0.f};

  int kvbeg = z * 768, kvend = kvbeg + 768;
  for (int kv0 = kvbeg; kv0 < kvend; kv0 += 128) {
    #pragma unroll
    for (int i = 0; i < 4; i++) {
      int ci = tid + (i << 8);
      int rK = ci >> 3, clK = ci & 7;
      int cgK = clK ^ (rK & 7);
      async16(&Kb[(size_t)(kv0 + rK) * DH + (cgK << 3)], &lK[(size_t)ci << 3]);
      int rV = ci >> 4, clV = ci & 15;
      int cgV = (clV & 8) | ((clV ^ (rV & 7)) & 7);
      async16(&Vb[(size_t)rV * S_TOT + kv0 + (cgV << 3)], &lV[(size_t)ci << 3]);
    }
    __syncthreads();

    floatx4 sacc[2][8];
    #pragma unroll
    for (int mi = 0; mi < 2; mi++)
      #pragma unroll
      for (int si = 0; si < 8; si++) sacc[mi][si] = zero4();
    #pragma unroll
    for (int si = 0; si < 8; si++) {
      int r = si * 16 + l15;
      #pragma unroll
      for (int kd = 0; kd < 2; kd++) {
        int c = (kd << 2) + quad;
        int cl = c ^ (r & 7);
        short8 kf = *(const short8*)&lK[r * 64 + (cl << 3)];
        sacc[0][si] = __builtin_amdgcn_mfma_f32_16x16x32_bf16(kf, qf[0][kd], sacc[0][si], 0, 0, 0);
        sacc[1][si] = __builtin_amdgcn_mfma_f32_16x16x32_bf16(kf, qf[1][kd], sacc[1][si], 0, 0, 0);
      }
    }

    #pragma unroll
    for (int mi = 0; mi < 2; mi++) {
      float rm = -1e30f;
      #pragma unroll
      for (int si = 0; si < 8; si++)
        #pragma unroll
        for (int r = 0; r < 4; r++) rm = fmaxf(rm, sacc[mi][si][r]);
      rm = fmaxf(rm, __shfl_xor(rm, 16));
      rm = fmaxf(rm, __shfl_xor(rm, 32));
      float mnew = fmaxf(mst[mi], rm);
      float al = __expf(mst[mi] - mnew);
      mst[mi] = mnew;
      float rs = 0.f;
      #pragma unroll
      for (int si = 0; si < 8; si++)
        #pragma unroll
        for (int r = 0; r < 4; r++) {
          float p = __expf(sacc[mi][si][r] - mnew);
          sacc[mi][si][r] = p;
          rs += p;
        }
      rs += __shfl_xor(rs, 16);
      rs += __shfl_xor(rs, 32);
      lst[mi] = lst[mi] * al + rs;
      #pragma unroll
      for (int dt = 0; dt < 4; dt++)
        #pragma unroll
        for (int r = 0; r < 4; r++) oacc[mi][dt][r] *= al;
    }

    #pragma unroll
    for (int si = 0; si < 8; si++) {
      s4b pb[2];
      #pragma unroll
      for (int mi = 0; mi < 2; mi++) {
        union { s4b v; unsigned u[2]; } p;
        p.u[0] = __builtin_amdgcn_perm(fbits(sacc[mi][si][1]), fbits(sacc[mi][si][0]), 0x07060302u);
        p.u[1] = __builtin_amdgcn_perm(fbits(sacc[mi][si][3]), fbits(sacc[mi][si][2]), 0x07060302u);
        pb[mi] = p.v;
      }
      #pragma unroll
      for (int dt = 0; dt < 4; dt++) {
        int r = dt * 16 + l15;
        int c = (si << 1) + (quad >> 1);
        int cl = (c & 8) | ((c ^ (r & 7)) & 7);
        s4b vf = *(const s4b*)&lV[r * 128 + (cl << 3) + ((quad & 1) << 2)];
        oacc[0][dt] = __builtin_amdgcn_mfma_f32_16x16x16bf16_1k(vf, pb[0], oacc[0][dt], 0, 0, 0);
        oacc[1][dt] = __builtin_amdgcn_mfma_f32_16x16x16bf16_1k(vf, pb[1], oacc[1][dt], 0, 0, 0);
      }
    }
    __syncthreads();
  }

  // write unnormalized partial O (bf16) + (m,l)
  u16* Ob = Op + (size_t)(z * 32 + bh) * S_TOT * DH;
  float2* mlb = ml + (size_t)(z * 32 + bh) * S_TOT;
  #pragma unroll
  for (int mi = 0; mi < 2; mi++) {
    int qg = q0 + wave * 32 + mi * 16 + l15;
    size_t base = (size_t)qg * DH;
    #pragma unroll
    for (int dt = 0; dt < 4; dt++) {
      s4b o;
      #pragma unroll
      for (int r = 0; r < 4; r++) o[r] = (short)f2bf(oacc[mi][dt][r]);
      *(s4b*)&Ob[base + dt * 16 + quad * 4] = o;
    }
    if (quad == 0) mlb[qg] = make_float2(mst[mi], lst[mi]);
  }
}

// ---------------- combine 3 KV-split partials -> attn_out ----------------
__global__ __launch_bounds__(256)
void attn_combine(const u16* __restrict__ Op, const float2* __restrict__ ml,
                  u16* __restrict__ O) {
  int tid = threadIdx.x;
  int row = blockIdx.x * 4 + (tid >> 6);     // bh*2304 + q, 0..73727
  int d = tid & 63;
  const size_t ZS = (size_t)32 * S_TOT;
  float2 a0 = ml[row], a1 = ml[ZS + row], a2 = ml[2 * ZS + row];
  float M = fmaxf(a0.x, fmaxf(a1.x, a2.x));
  float w0 = __expf(a0.x - M), w1 = __expf(a1.x - M), w2 = __expf(a2.x - M);
  float L = w0 * a0.y + w1 * a1.y + w2 * a2.y;
  size_t stride = ZS * DH;
  size_t idx = (size_t)row * DH + d;
  float o = w0 * bf2f(Op[idx]) + w1 * bf2f(Op[stride + idx]) + w2 * bf2f(Op[2 * stride + idx]);
  o /= L;
  int bh = row / S_TOT, q = row - bh * S_TOT;
  int b = bh >> 4, h = bh & 15;
  O[(((size_t)(b * S_TOT + q)) << 10) + h * 64 + d] = f2bf(o);
}

// ---------------- launch ----------------
extern "C" void kernel_launch(void* const* d_in, const int* in_sizes, int n_in,
                              void* d_out, int out_size, void* d_ws, size_t ws_size,
                              hipStream_t stream) {
  const float* x       = (const float*)d_in[0];
  const float* mod     = (const float*)d_in[1];
  const float* cond    = (const float*)d_in[2];
  const float* w_adaln = (const float*)d_in[3];
  const float* b_adaln = (const float*)d_in[4];
  const float* w_qkv   = (const float*)d_in[5];
  const float* b_qkv   = (const float*)d_in[6];
  const float* w_proj  = (const float*)d_in[7];
  const float* b_proj  = (const float*)d_in[8];
  const float* w_s1    = (const float*)d_in[9];
  const float* b_s1    = (const float*)d_in[10];
  const float* w_s2    = (const float*)d_in[11];
  const float* b_s2    = (const float*)d_in[12];
  const float* w_d1    = (const float*)d_in[13];
  const float* b_d1    = (const float*)d_in[14];
  const float* w_d2    = (const float*)d_in[15];
  const float* b_d2    = (const float*)d_in[16];

  float* outx = (float*)d_out;
  float* outc = outx + (size_t)2 * N_SEQ * C_DIM;

  char* w = (char*)d_ws;
  auto alloc = [&](size_t bytes) { char* p = w; w += (bytes + 255) & ~(size_t)255; return p; };
  float* m_ws  = (float*)alloc(12288 * 4);
  u16* wqkvT   = (u16*)alloc((size_t)3072 * 1024 * 2);
  u16* wprojT  = (u16*)alloc((size_t)1024 * 1024 * 2);
  u16* ws1T    = (u16*)alloc((size_t)4096 * 1024 * 2);
  u16* ws2T    = (u16*)alloc((size_t)4096 * 1024 * 2);
  u16* wd1T    = (u16*)alloc((size_t)4096 * 1024 * 2);
  u16* wd2T    = (u16*)alloc((size_t)4096 * 1024 * 2);
  u16* joint   = (u16*)alloc((size_t)4608 * 1024 * 2);   // reused as attn_out
  u16* Qb      = (u16*)alloc((size_t)4718592 * 2);
  u16* Kb      = (u16*)alloc((size_t)4718592 * 2);
  u16* Vb      = (u16*)alloc((size_t)4718592 * 2);
  u16* Vtb     = (u16*)alloc((size_t)4718592 * 2);
  u16* h1      = (u16*)alloc((size_t)4608 * 4096 * 2);   // 37.7 MB; O_part+ml alias (dead here)
  u16* xln2 = Qb;          // alias: Q dead after flash
  u16* cln2 = Kb;          // alias: K dead after flash
  u16* attn_out = joint;   // alias: joint dead after qkv GEMM
  u16* O_part = h1;                                    // 3*32*2304*64 bf16 = 28.3 MB
  float2* ml = (float2*)(h1 + (size_t)3 * 32 * S_TOT * DH);  // 1.77 MB, fits in h1

  size_t needed = (size_t)(w - (char*)d_ws);
  if (needed > ws_size) {
    hipMemsetAsync(d_out, 0, (size_t)out_size * 4, stream);
    return;
  }

  hipMemsetAsync(m_ws, 0, 12288 * 4, stream);
  adaln_mod<<<dim3(24, 2, 8), 256, 0, stream>>>(mod, w_adaln, m_ws);

  wtrans_all<<<20480, 256, 0, stream>>>(w_qkv, w_proj, w_s1, w_s2, w_d1, w_d2,
                                        wqkvT, wprojT, ws1T, ws2T, wd1T, wd2T);

  ln_mod<0><<<4608, 256, 0, stream>>>(x, cond, m_ws, b_adaln, nullptr, nullptr, joint);

  gemm_k<0, 128><<<dim3(24, 36), 256, 0, stream>>>(joint, wqkvT, b_qkv, 1024,
      nullptr, nullptr, nullptr, nullptr, nullptr, nullptr, Qb, Kb, Vb);

  vtrans<<<dim3(36, 32), 256, 0, stream>>>(Vb, Vtb);
  flash_attn<<<dim3(18, 32, 3), 256, 0, stream>>>(Qb, Kb, Vtb, O_part, ml);
  attn_combine<<<18432, 256, 0, stream>>>(O_part, ml, attn_out);

  gemm_k<1, 64><<<dim3(8, 72), 256, 0, stream>>>(attn_out, wprojT, b_proj, 1024,
      m_ws, b_adaln, x, cond, outx, outc, nullptr, nullptr, nullptr);

  ln_mod<3072><<<4608, 256, 0, stream>>>(outx, outc, m_ws, b_adaln, xln2, cln2, nullptr);

  mlp1<<<dim3(32, 36), 256, 0, stream>>>(xln2, cln2, ws1T, wd1T, b_s1, b_d1, h1);
  mlp2<<<dim3(8, 36, 2), 256, 0, stream>>>(h1, ws2T, wd2T, b_s2, b_d2,
                                           m_ws, b_adaln, outx, outc);
}